// Round 9
// baseline (424.006 us; speedup 1.0000x reference)
//
#include <hip/hip_runtime.h>
#include <hip/hip_bf16.h>

typedef __attribute__((ext_vector_type(4))) float  f32x4;
typedef __attribute__((ext_vector_type(8))) short  bf16x8;
typedef __attribute__((ext_vector_type(4))) short  bf16x4;

#define MFMA16(a, b, c) __builtin_amdgcn_mfma_f32_16x16x32_bf16((a), (b), (c), 0, 0, 0)

__device__ __forceinline__ short f2bf(float f) {
  return __builtin_bit_cast(short, __float2bfloat16(f));
}
__device__ __forceinline__ float bf2f(short b) {
  return __builtin_bit_cast(float, ((unsigned)(unsigned short)b) << 16);
}

__device__ __forceinline__ void sync_lds() {
  asm volatile("s_waitcnt lgkmcnt(0)" ::: "memory");
  __builtin_amdgcn_s_barrier();
  asm volatile("" ::: "memory");
}

constexpr int L = 2048, D = 64, KT = 64, NT = L / KT;   // 32 k-tiles
constexpr int NHEAD = 64;
constexpr int QB = 128, NQT = L / QB;                    // 16 q-tiles -> grid 1024
constexpr float QSCALE = 0.18033688011112042f;           // 0.125*log2(e)
constexpr size_t BF_ELEMS = (size_t)NHEAD * L * D;       // per tensor
constexpr size_t WS_NEED = 3 * BF_ELEMS * sizeof(short) + (size_t)NHEAD * L * sizeof(float);

// ============ prep: f32 -> bf16 (Q scaled; V transposed per head) ============
__global__ __launch_bounds__(256)
void sdpa_prep(const float* __restrict__ Q, const float* __restrict__ K,
               const float* __restrict__ V,
               short* __restrict__ Qb, short* __restrict__ Kb,
               short* __restrict__ Vtb)
{
  __shared__ short Tl[64 * 72];
  const int t = threadIdx.x;
  const int head = blockIdx.x >> 5, kt = blockIdx.x & 31;
  const long base = (long)head * L * D + (long)kt * 64 * D;

  {
    const float* qp = Q + base + t * 16;
    short*       qo = Qb + base + t * 16;
    bf16x8 y0, y1;
    #pragma unroll
    for (int j = 0; j < 8; ++j) {
      y0[j] = f2bf(qp[j]     * QSCALE);
      y1[j] = f2bf(qp[8 + j] * QSCALE);
    }
    *(bf16x8*)qo = y0; *(bf16x8*)(qo + 8) = y1;
  }
  {
    const float* kp = K + base + t * 16;
    short*       ko = Kb + base + t * 16;
    bf16x8 y0, y1;
    #pragma unroll
    for (int j = 0; j < 8; ++j) { y0[j] = f2bf(kp[j]); y1[j] = f2bf(kp[8 + j]); }
    *(bf16x8*)ko = y0; *(bf16x8*)(ko + 8) = y1;
  }
  {
    const int kr0 = (t >> 4) * 4, d0 = (t & 15) * 4;
    const float* vp = V + base;
    f32x4 r[4];
    #pragma unroll
    for (int i = 0; i < 4; ++i) r[i] = *(const f32x4*)(vp + (kr0 + i) * D + d0);
    #pragma unroll
    for (int j = 0; j < 4; ++j) {
      bf16x4 y;
      #pragma unroll
      for (int i = 0; i < 4; ++i) y[i] = f2bf(r[i][j]);
      *(bf16x4*)(&Tl[(d0 + j) * 72 + kr0]) = y;
    }
  }
  __syncthreads();
  {
    const int d = t >> 2, k0 = (t & 3) * 16;
    bf16x8 a = *(const bf16x8*)(&Tl[d * 72 + k0]);
    bf16x8 b = *(const bf16x8*)(&Tl[d * 72 + k0 + 8]);
    short* vo = Vtb + (long)head * D * L + (long)d * L + kt * 64 + k0;
    *(bf16x8*)vo = a; *(bf16x8*)(vo + 8) = b;
  }
}

// ============ rowsum: rinv for all (head, q) -> ws ============
__global__ __launch_bounds__(256, 4)
void sdpa_rowsum(const short* __restrict__ Qb, const short* __restrict__ Kb,
                 float* __restrict__ rinv_out)
{
  __shared__ short Klds[2][KT * D];

  const int t = threadIdx.x, lane = t & 63, w = t >> 6;
  const int qr = lane & 15, g = lane >> 4;

  const int bid = blockIdx.x;
  const int wid = ((bid & 7) << 7) | (bid >> 3);
  const int head = wid >> 4, qt = wid & 15;
  const long hoff = (long)head * L * D;
  const int qrow0 = qt * QB + w * 32;

  bf16x8 qfrag[2][2];
  #pragma unroll
  for (int h = 0; h < 2; ++h) {
    const short* qbp = Qb + hoff + (long)(qrow0 + 16 * h + qr) * D + g * 8;
    qfrag[h][0] = *(const bf16x8*)qbp;
    qfrag[h][1] = *(const bf16x8*)(qbp + 32);
  }

  const short* Kbase = Kb + hoff;
  bf16x8 kreg[2];
  const int krow = t >> 2, kd0 = (t & 3) * 16;

  auto loadK = [&](int kt) {
    const short* kp = Kbase + (long)(kt * KT + krow) * D + kd0;
    kreg[0] = *(const bf16x8*)kp;
    kreg[1] = *(const bf16x8*)(kp + 8);
  };
  auto writeK = [&](int buf) {
    const int sw = (krow & 7) << 3;
    *(bf16x8*)(&Klds[buf][krow * 64 + (kd0 ^ sw)])       = kreg[0];
    *(bf16x8*)(&Klds[buf][krow * 64 + ((kd0 + 8) ^ sw)]) = kreg[1];
  };

  loadK(0); writeK(0);
  sync_lds();
  float rsum0 = 0.f, rsum1 = 0.f;
  for (int kt = 0; kt < NT; ++kt) {
    const int cur = kt & 1;
    if (kt + 1 < NT) loadK(kt + 1);
    #pragma unroll
    for (int f = 0; f < 4; ++f) {
      f32x4 s0 = (f32x4){0.f,0.f,0.f,0.f};
      f32x4 s1 = (f32x4){0.f,0.f,0.f,0.f};
      int kr = f * 16 + qr;
      #pragma unroll
      for (int c = 0; c < 2; ++c) {
        int d0c = g * 8 + 32 * c;
        bf16x8 a = *(const bf16x8*)(&Klds[cur][kr * 64 + (d0c ^ ((kr & 7) << 3))]);
        s0 = MFMA16(a, qfrag[0][c], s0);
        s1 = MFMA16(a, qfrag[1][c], s1);
      }
      #pragma unroll
      for (int r = 0; r < 4; ++r) {
        rsum0 += __builtin_amdgcn_exp2f(s0[r]);
        rsum1 += __builtin_amdgcn_exp2f(s1[r]);
      }
    }
    if (kt + 1 < NT) writeK(cur ^ 1);
    sync_lds();
  }
  rsum0 += __shfl_xor(rsum0, 16); rsum0 += __shfl_xor(rsum0, 32);
  rsum1 += __shfl_xor(rsum1, 16); rsum1 += __shfl_xor(rsum1, 32);
  if (lane < 16) {
    float* ro = rinv_out + (long)head * L + qrow0;
    ro[qr]      = 1.f / rsum0;
    ro[16 + qr] = 1.f / rsum1;
  }
}

// ============ main: single pass, NT stores for attn/out ============
__global__ __launch_bounds__(256, 4)
void sdpa_main(const short* __restrict__ Qb, const short* __restrict__ Kb,
               const short* __restrict__ Vtb, const float* __restrict__ rinv_ws,
               float* __restrict__ out, float* __restrict__ attn)
{
  __shared__ short Klds[2][KT * D];     // 16 KB
  __shared__ short Vlds[2][D * KT];     // 16 KB
  __shared__ short Plds[4][16 * KT];    // 8 KB (per-wave, reused per q-half)

  const int t = threadIdx.x, lane = t & 63, w = t >> 6;
  const int qr = lane & 15, g = lane >> 4;

  // bijective XCD swizzle (1024 % 8 == 0)
  const int bid = blockIdx.x;
  const int wid = ((bid & 7) << 7) | (bid >> 3);
  const int head = wid >> 4, qt = wid & 15;
  const long hoff = (long)head * L * D;
  const int qrow0 = qt * QB + w * 32;

  const float rinv0 = rinv_ws[(long)head * L + qrow0 + qr];
  const float rinv1 = rinv_ws[(long)head * L + qrow0 + 16 + qr];

  bf16x8 qfrag[2][2];
  #pragma unroll
  for (int h = 0; h < 2; ++h) {
    const short* qbp = Qb + hoff + (long)(qrow0 + 16 * h + qr) * D + g * 8;
    qfrag[h][0] = *(const bf16x8*)qbp;
    qfrag[h][1] = *(const bf16x8*)(qbp + 32);
  }

  const short* Kbase = Kb + hoff;
  const short* Vbase = Vtb + (long)head * D * L;

  bf16x8 kreg[2], vreg[2];
  const int krow = t >> 2, kd0 = (t & 3) * 16;

  auto loadK = [&](int kt) {
    const short* kp = Kbase + (long)(kt * KT + krow) * D + kd0;
    kreg[0] = *(const bf16x8*)kp;
    kreg[1] = *(const bf16x8*)(kp + 8);
  };
  auto writeK = [&](int buf) {
    const int sw = (krow & 7) << 3;
    *(bf16x8*)(&Klds[buf][krow * 64 + (kd0 ^ sw)])       = kreg[0];
    *(bf16x8*)(&Klds[buf][krow * 64 + ((kd0 + 8) ^ sw)]) = kreg[1];
  };
  auto loadV = [&](int kt) {
    const short* vp = Vbase + (long)krow * L + kt * KT + kd0;
    vreg[0] = *(const bf16x8*)vp;
    vreg[1] = *(const bf16x8*)(vp + 8);
  };
  auto writeV = [&](int buf) {
    const int sw = (krow & 7) << 3;
    *(bf16x8*)(&Vlds[buf][krow * 64 + (kd0 ^ sw)])       = vreg[0];
    *(bf16x8*)(&Vlds[buf][krow * 64 + ((kd0 + 8) ^ sw)]) = vreg[1];
  };

  auto computeS2 = [&](int buf, f32x4 s0[4], f32x4 s1[4]) {
    #pragma unroll
    for (int f = 0; f < 4; ++f) {
      s0[f] = (f32x4){0.f, 0.f, 0.f, 0.f};
      s1[f] = (f32x4){0.f, 0.f, 0.f, 0.f};
      int kr = f * 16 + qr;
      #pragma unroll
      for (int c = 0; c < 2; ++c) {
        int d0c = g * 8 + 32 * c;
        bf16x8 a = *(const bf16x8*)(&Klds[buf][kr * 64 + (d0c ^ ((kr & 7) << 3))]);
        s0[f] = MFMA16(a, qfrag[0][c], s0[f]);
        s1[f] = MFMA16(a, qfrag[1][c], s1[f]);
      }
    }
  };

  f32x4 o0[4] = {{0.f,0.f,0.f,0.f},{0.f,0.f,0.f,0.f},{0.f,0.f,0.f,0.f},{0.f,0.f,0.f,0.f}};
  f32x4 o1[4] = {{0.f,0.f,0.f,0.f},{0.f,0.f,0.f,0.f},{0.f,0.f,0.f,0.f},{0.f,0.f,0.f,0.f}};
  float* ap0 = attn + (long)head * L * L + (long)(qrow0 + qr) * L;
  float* ap1 = ap0 + 16 * L;

  auto doHalf = [&](f32x4 s[4], float rinv, float* ap, f32x4 o[4], int cur, int kt) {
    #pragma unroll
    for (int f = 0; f < 4; ++f) {
      f32x4 pf;
      #pragma unroll
      for (int r = 0; r < 4; ++r)
        pf[r] = __builtin_amdgcn_exp2f(s[f][r]) * rinv;
      // non-temporal: attn is write-once streaming -> don't allocate in L2,
      // keep K/V resident instead
      __builtin_nontemporal_store(pf, (f32x4*)(ap + kt * KT + f * 16 + g * 4));
      bf16x4 p;
      #pragma unroll
      for (int r = 0; r < 4; ++r) p[r] = f2bf(pf[r]);
      int k0 = f * 16 + g * 4;
      *(bf16x4*)(&Plds[w][qr * 64 + (k0 ^ ((qr & 7) << 3))]) = p;
    }
    __builtin_amdgcn_wave_barrier();   // P writes before PV reads (wave-private)
    #pragma unroll
    for (int kc = 0; kc < 2; ++kc) {
      int k0 = kc * 32 + g * 8;
      bf16x8 pa = *(const bf16x8*)(&Plds[w][qr * 64 + (k0 ^ ((qr & 7) << 3))]);
      #pragma unroll
      for (int fr = 0; fr < 4; ++fr) {
        int d = fr * 16 + qr;
        bf16x8 vb = *(const bf16x8*)(&Vlds[cur][d * 64 + (k0 ^ ((d & 7) << 3))]);
        o[fr] = MFMA16(pa, vb, o[fr]);
      }
    }
    __builtin_amdgcn_wave_barrier();   // PV reads before next half's P writes (WAR)
  };

  loadK(0); loadV(0);
  writeK(0); writeV(0);
  sync_lds();

  for (int kt = 0; kt < NT; ++kt) {
    const int cur = kt & 1;
    if (kt + 1 < NT) { loadK(kt + 1); loadV(kt + 1); }

    f32x4 s0[4], s1[4];
    computeS2(cur, s0, s1);

    doHalf(s0, rinv0, ap0, o0, cur, kt);
    doHalf(s1, rinv1, ap1, o1, cur, kt);

    if (kt + 1 < NT) { writeK(cur ^ 1); writeV(cur ^ 1); }
    sync_lds();
  }

  float* op = out + hoff + (long)qrow0 * D;
  #pragma unroll
  for (int fr = 0; fr < 4; ++fr)
    #pragma unroll
    for (int r = 0; r < 4; ++r) {
      __builtin_nontemporal_store(o0[fr][r], op + (long)(g * 4 + r) * D + fr * 16 + qr);
      __builtin_nontemporal_store(o1[fr][r], op + (long)(16 + g * 4 + r) * D + fr * 16 + qr);
    }
}

// ============ fallback (round-5 proven kernel, f32-staged) ============
__global__ __launch_bounds__(256, 4)
void sdpa_fused(const float* __restrict__ Q, const float* __restrict__ K,
                const float* __restrict__ V, float* __restrict__ out,
                float* __restrict__ attn)
{
  __shared__ short Klds[2][KT * D];
  __shared__ short Vlds[2][D * KT];
  __shared__ short Plds[4][16 * KT];

  const int t = threadIdx.x, lane = t & 63, w = t >> 6;
  const int qr = lane & 15, g = lane >> 4;
  const int head = blockIdx.x >> 5, qt = blockIdx.x & 31;
  const long hoff = (long)head * L * D;
  const int qrow0 = qt * 64 + w * 16;

  bf16x8 qfrag[2];
  {
    const float* qp = Q + hoff + (long)(qrow0 + qr) * D + g * 8;
    #pragma unroll
    for (int c = 0; c < 2; ++c)
      #pragma unroll
      for (int j = 0; j < 8; ++j)
        qfrag[c][j] = f2bf(qp[32 * c + j] * QSCALE);
  }

  const float* Kbase = K + hoff;
  const float* Vbase = V + hoff;
  f32x4 kreg[4], vreg[4];

  auto loadK = [&](int kt) {
    const float* kp = Kbase + (long)kt * KT * D;
    #pragma unroll
    for (int c = 0; c < 4; ++c)
      kreg[c] = *(const f32x4*)(kp + (t + 256 * c) * 4);
  };
  auto writeK = [&](int buf) {
    #pragma unroll
    for (int c = 0; c < 4; ++c) {
      int f = t + 256 * c;
      int kr = f >> 4, col = (f & 15) * 4;
      bf16x4 y;
      #pragma unroll
      for (int i = 0; i < 4; ++i) y[i] = f2bf(kreg[c][i]);
      *(bf16x4*)(&Klds[buf][kr * 64 + (col ^ ((kr & 7) << 3))]) = y;
    }
  };
  auto loadV = [&](int kt) {
    const float* vp = Vbase + (long)kt * KT * D;
    int kr0 = (t >> 4) * 4, d0 = (t & 15) * 4;
    #pragma unroll
    for (int i = 0; i < 4; ++i)
      vreg[i] = *(const f32x4*)(vp + (kr0 + i) * D + d0);
  };
  auto writeV = [&](int buf) {
    int kr0 = (t >> 4) * 4, d0 = (t & 15) * 4;
    #pragma unroll
    for (int j = 0; j < 4; ++j) {
      bf16x4 y;
      #pragma unroll
      for (int i = 0; i < 4; ++i) y[i] = f2bf(vreg[i][j]);
      int d = d0 + j;
      *(bf16x4*)(&Vlds[buf][d * 64 + (kr0 ^ ((d & 7) << 3))]) = y;
    }
  };
  auto computeS = [&](int buf, f32x4 s[4]) {
    #pragma unroll
    for (int f = 0; f < 4; ++f) {
      s[f] = (f32x4){0.f, 0.f, 0.f, 0.f};
      int kr = f * 16 + qr;
      #pragma unroll
      for (int c = 0; c < 2; ++c) {
        int d0c = g * 8 + 32 * c;
        bf16x8 a = *(const bf16x8*)(&Klds[buf][kr * 64 + (d0c ^ ((kr & 7) << 3))]);
        s[f] = MFMA16(a, qfrag[c], s[f]);
      }
    }
  };

  loadK(0); writeK(0);
  sync_lds();
  float rsum = 0.f;
  for (int kt = 0; kt < NT; ++kt) {
    const int cur = kt & 1;
    if (kt + 1 < NT) loadK(kt + 1);
    f32x4 s[4];
    computeS(cur, s);
    #pragma unroll
    for (int f = 0; f < 4; ++f)
      #pragma unroll
      for (int r = 0; r < 4; ++r)
        rsum += __builtin_amdgcn_exp2f(s[f][r]);
    if (kt + 1 < NT) writeK(cur ^ 1);
    sync_lds();
  }
  rsum += __shfl_xor(rsum, 16);
  rsum += __shfl_xor(rsum, 32);
  const float rinv = 1.f / rsum;

  f32x4 o[4] = {{0.f,0.f,0.f,0.f},{0.f,0.f,0.f,0.f},{0.f,0.f,0.f,0.f},{0.f,0.f,0.f,0.f}};
  float* ap_base = attn + (long)head * L * L + (long)qrow0 * L;

  loadK(0); loadV(0);
  writeK(0); writeV(0);
  sync_lds();

  for (int kt = 0; kt < NT; ++kt) {
    const int cur = kt & 1;
    if (kt + 1 < NT) { loadK(kt + 1); loadV(kt + 1); }

    f32x4 s[4];
    computeS(cur, s);

    #pragma unroll
    for (int f = 0; f < 4; ++f) {
      bf16x4 p;
      #pragma unroll
      for (int r = 0; r < 4; ++r)
        p[r] = f2bf(__builtin_amdgcn_exp2f(s[f][r]) * rinv);
      int k0 = f * 16 + g * 4;
      *(bf16x4*)(&Plds[w][qr * 64 + (k0 ^ ((qr & 7) << 3))]) = p;
    }
    __builtin_amdgcn_wave_barrier();

    float* ap = ap_base + (long)kt * KT;
    #pragma unroll
    for (int i = 0; i < 4; ++i) {
      int r = 4 * i + g, col = 4 * qr;
      bf16x4 pb = *(const bf16x4*)(&Plds[w][r * 64 + (col ^ ((r & 7) << 3))]);
      f32x4 pf;
      #pragma unroll
      for (int j = 0; j < 4; ++j) pf[j] = bf2f(pb[j]);
      *(f32x4*)(ap + (long)r * L + col) = pf;
    }

    #pragma unroll
    for (int kc = 0; kc < 2; ++kc) {
      int k0 = kc * 32 + g * 8;
      bf16x8 pa = *(const bf16x8*)(&Plds[w][qr * 64 + (k0 ^ ((qr & 7) << 3))]);
      #pragma unroll
      for (int fr = 0; fr < 4; ++fr) {
        int d = fr * 16 + qr;
        bf16x8 vb = *(const bf16x8*)(&Vlds[cur][d * 64 + (k0 ^ ((d & 7) << 3))]);
        o[fr] = MFMA16(pa, vb, o[fr]);
      }
    }

    if (kt + 1 < NT) { writeK(cur ^ 1); writeV(cur ^ 1); }
    sync_lds();
  }

  float* op = out + hoff + (long)qrow0 * D;
  #pragma unroll
  for (int fr = 0; fr < 4; ++fr)
    #pragma unroll
    for (int r = 0; r < 4; ++r) {
      int qq = g * 4 + r;
      op[(long)qq * D + fr * 16 + qr] = o[fr][r];
    }
}

extern "C" void kernel_launch(void* const* d_in, const int* in_sizes, int n_in,
                              void* d_out, int out_size, void* d_ws, size_t ws_size,
                              hipStream_t stream) {
  const float* q = (const float*)d_in[0];
  const float* k = (const float*)d_in[1];
  const float* v = (const float*)d_in[2];
  float* out  = (float*)d_out;                          // (B,H,L,D)
  float* attn = (float*)d_out + (size_t)NHEAD * L * D;  // (B,H,L,L)

  dim3 block(256);

  if (ws_size >= WS_NEED) {
    short* Qb   = (short*)d_ws;
    short* Kb   = Qb + BF_ELEMS;
    short* Vtb  = Kb + BF_ELEMS;
    float* rinv = (float*)(Vtb + BF_ELEMS);
    hipLaunchKernelGGL(sdpa_prep,   dim3(NHEAD * NT),  block, 0, stream, q, k, v, Qb, Kb, Vtb);
    hipLaunchKernelGGL(sdpa_rowsum, dim3(NHEAD * NQT), block, 0, stream, Qb, Kb, rinv);
    hipLaunchKernelGGL(sdpa_main,   dim3(NHEAD * NQT), block, 0, stream, Qb, Kb, Vtb, rinv, out, attn);
  } else {
    hipLaunchKernelGGL(sdpa_fused, dim3(NHEAD * NT), block, 0, stream, q, k, v, out, attn);
  }
}

// Round 10
// 359.697 us; speedup vs baseline: 1.1788x; 1.1788x over previous
//
#include <hip/hip_runtime.h>
#include <hip/hip_bf16.h>

typedef __attribute__((ext_vector_type(4))) float  f32x4;
typedef __attribute__((ext_vector_type(8))) short  bf16x8;
typedef __attribute__((ext_vector_type(4))) short  bf16x4;

#define MFMA16(a, b, c) __builtin_amdgcn_mfma_f32_16x16x32_bf16((a), (b), (c), 0, 0, 0)

__device__ __forceinline__ short f2bf(float f) {
  return __builtin_bit_cast(short, __float2bfloat16(f));
}
__device__ __forceinline__ float bf2f(short b) {
  return __builtin_bit_cast(float, ((unsigned)(unsigned short)b) << 16);
}

__device__ __forceinline__ void sync_lds() {
  asm volatile("s_waitcnt lgkmcnt(0)" ::: "memory");
  __builtin_amdgcn_s_barrier();
  asm volatile("" ::: "memory");
}

constexpr int L = 2048, D = 64, KT = 64, NT = L / KT;   // 32 k-tiles
constexpr int NHEAD = 64;
constexpr int QB = 128, NQT = L / QB;                    // 16 q-tiles -> grid 1024
constexpr float QSCALE = 0.18033688011112042f;           // 0.125*log2(e)
constexpr size_t BF_ELEMS = (size_t)NHEAD * L * D;       // per tensor
constexpr size_t WS_NEED = 3 * BF_ELEMS * sizeof(short) + (size_t)NHEAD * L * sizeof(float);

// ============ prepV: V f32 -> bf16 transposed per head ============
__global__ __launch_bounds__(256)
void sdpa_prepV(const float* __restrict__ V, short* __restrict__ Vtb)
{
  __shared__ short Tl[64 * 72];
  const int t = threadIdx.x;
  const int head = blockIdx.x >> 5, kt = blockIdx.x & 31;
  const long base = (long)head * L * D + (long)kt * 64 * D;

  const int kr0 = (t >> 4) * 4, d0 = (t & 15) * 4;
  const float* vp = V + base;
  f32x4 r[4];
  #pragma unroll
  for (int i = 0; i < 4; ++i) r[i] = *(const f32x4*)(vp + (kr0 + i) * D + d0);
  #pragma unroll
  for (int j = 0; j < 4; ++j) {
    bf16x4 y;
    #pragma unroll
    for (int i = 0; i < 4; ++i) y[i] = f2bf(r[i][j]);
    *(bf16x4*)(&Tl[(d0 + j) * 72 + kr0]) = y;
  }
  __syncthreads();
  const int d = t >> 2, k0 = (t & 3) * 16;
  bf16x8 a = *(const bf16x8*)(&Tl[d * 72 + k0]);
  bf16x8 b = *(const bf16x8*)(&Tl[d * 72 + k0 + 8]);
  short* vo = Vtb + (long)head * D * L + (long)d * L + kt * 64 + k0;
  *(bf16x8*)vo = a; *(bf16x8*)(vo + 8) = b;
}

// ===== rowsum2: f32 Q/K in; rinv out; Qb/Kb bf16 written as side effects =====
__global__ __launch_bounds__(256, 4)
void sdpa_rowsum2(const float* __restrict__ Qf, const float* __restrict__ Kf,
                  short* __restrict__ Qb, short* __restrict__ Kb,
                  float* __restrict__ rinv_out)
{
  __shared__ short Klds[2][KT * D];

  const int t = threadIdx.x, lane = t & 63, w = t >> 6;
  const int qr = lane & 15, g = lane >> 4;

  const int bid = blockIdx.x;
  const int wid = ((bid & 7) << 7) | (bid >> 3);
  const int head = wid >> 4, qt = wid & 15;
  const long hoff = (long)head * L * D;
  const int qrow0 = qt * QB + w * 32;

  // stream-convert this block's 128 Q rows -> Qb (32 elems/thread)
  {
    const float* qp = Qf + hoff + (long)qt * QB * D + t * 32;
    short*       qo = Qb + hoff + (long)qt * QB * D + t * 32;
    #pragma unroll
    for (int c = 0; c < 4; ++c) {
      f32x4 a = *(const f32x4*)(qp + c * 8);
      f32x4 b = *(const f32x4*)(qp + c * 8 + 4);
      bf16x8 y;
      #pragma unroll
      for (int j = 0; j < 4; ++j) {
        y[j]     = f2bf(a[j] * QSCALE);
        y[4 + j] = f2bf(b[j] * QSCALE);
      }
      *(bf16x8*)(qo + c * 8) = y;
    }
  }

  // qfrag directly from f32 Q (L2-hot)
  bf16x8 qfrag[2][2];
  #pragma unroll
  for (int h = 0; h < 2; ++h)
    #pragma unroll
    for (int c = 0; c < 2; ++c) {
      const float* qp = Qf + hoff + (long)(qrow0 + 16 * h + qr) * D + g * 8 + 32 * c;
      f32x4 a = *(const f32x4*)qp;
      f32x4 b = *(const f32x4*)(qp + 4);
      #pragma unroll
      for (int j = 0; j < 4; ++j) {
        qfrag[h][c][j]     = f2bf(a[j] * QSCALE);
        qfrag[h][c][4 + j] = f2bf(b[j] * QSCALE);
      }
    }

  const float* KfH = Kf + hoff;
  short*       KbH = Kb + hoff;
  const int krow = t >> 2, kd0 = (t & 3) * 16;
  f32x4 kf[4];
  bf16x8 kb0, kb1;

  auto loadK = [&](int kt) {
    const float* kp = KfH + (long)(kt * KT + krow) * D + kd0;
    #pragma unroll
    for (int i = 0; i < 4; ++i) kf[i] = *(const f32x4*)(kp + 4 * i);
  };
  auto cvtK = [&]() {
    #pragma unroll
    for (int j = 0; j < 8; ++j) {
      kb0[j] = f2bf(kf[j >> 2][j & 3]);
      kb1[j] = f2bf(kf[2 + (j >> 2)][j & 3]);
    }
  };
  auto writeKlds = [&](int buf) {
    const int sw = (krow & 7) << 3;
    *(bf16x8*)(&Klds[buf][krow * 64 + (kd0 ^ sw)])       = kb0;
    *(bf16x8*)(&Klds[buf][krow * 64 + ((kd0 + 8) ^ sw)]) = kb1;
  };
  auto maybeWriteKb = [&](int kt) {   // each block owns k-tiles 2qt, 2qt+1
    if ((kt >> 1) == qt) {
      short* ko = KbH + (long)(kt * KT + krow) * D + kd0;
      *(bf16x8*)ko = kb0;
      *(bf16x8*)(ko + 8) = kb1;
    }
  };

  loadK(0); cvtK(); writeKlds(0); maybeWriteKb(0);
  sync_lds();
  float rsum0 = 0.f, rsum1 = 0.f;
  for (int kt = 0; kt < NT; ++kt) {
    const int cur = kt & 1;
    if (kt + 1 < NT) loadK(kt + 1);
    #pragma unroll
    for (int f = 0; f < 4; ++f) {
      f32x4 s0 = (f32x4){0.f,0.f,0.f,0.f};
      f32x4 s1 = (f32x4){0.f,0.f,0.f,0.f};
      int kr = f * 16 + qr;
      #pragma unroll
      for (int c = 0; c < 2; ++c) {
        int d0c = g * 8 + 32 * c;
        bf16x8 a = *(const bf16x8*)(&Klds[cur][kr * 64 + (d0c ^ ((kr & 7) << 3))]);
        s0 = MFMA16(a, qfrag[0][c], s0);
        s1 = MFMA16(a, qfrag[1][c], s1);
      }
      #pragma unroll
      for (int r = 0; r < 4; ++r) {
        rsum0 += __builtin_amdgcn_exp2f(s0[r]);
        rsum1 += __builtin_amdgcn_exp2f(s1[r]);
      }
    }
    if (kt + 1 < NT) { cvtK(); writeKlds(cur ^ 1); maybeWriteKb(kt + 1); }
    sync_lds();
  }
  rsum0 += __shfl_xor(rsum0, 16); rsum0 += __shfl_xor(rsum0, 32);
  rsum1 += __shfl_xor(rsum1, 16); rsum1 += __shfl_xor(rsum1, 32);
  if (lane < 16) {
    float* ro = rinv_out + (long)head * L + qrow0;
    ro[qr]      = 1.f / rsum0;
    ro[16 + qr] = 1.f / rsum1;
  }
}

// ============ main: single pass (round-8 structure, plain stores) ============
__global__ __launch_bounds__(256, 4)
void sdpa_main(const short* __restrict__ Qb, const short* __restrict__ Kb,
               const short* __restrict__ Vtb, const float* __restrict__ rinv_ws,
               float* __restrict__ out, float* __restrict__ attn)
{
  __shared__ short Klds[2][KT * D];     // 16 KB
  __shared__ short Vlds[2][D * KT];     // 16 KB
  __shared__ short Plds[4][16 * KT];    // 8 KB (per-wave, reused per q-half)

  const int t = threadIdx.x, lane = t & 63, w = t >> 6;
  const int qr = lane & 15, g = lane >> 4;

  const int bid = blockIdx.x;
  const int wid = ((bid & 7) << 7) | (bid >> 3);
  const int head = wid >> 4, qt = wid & 15;
  const long hoff = (long)head * L * D;
  const int qrow0 = qt * QB + w * 32;

  const float rinv0 = rinv_ws[(long)head * L + qrow0 + qr];
  const float rinv1 = rinv_ws[(long)head * L + qrow0 + 16 + qr];

  bf16x8 qfrag[2][2];
  #pragma unroll
  for (int h = 0; h < 2; ++h) {
    const short* qbp = Qb + hoff + (long)(qrow0 + 16 * h + qr) * D + g * 8;
    qfrag[h][0] = *(const bf16x8*)qbp;
    qfrag[h][1] = *(const bf16x8*)(qbp + 32);
  }

  const short* Kbase = Kb + hoff;
  const short* Vbase = Vtb + (long)head * D * L;

  bf16x8 kreg[2], vreg[2];
  const int krow = t >> 2, kd0 = (t & 3) * 16;

  auto loadK = [&](int kt) {
    const short* kp = Kbase + (long)(kt * KT + krow) * D + kd0;
    kreg[0] = *(const bf16x8*)kp;
    kreg[1] = *(const bf16x8*)(kp + 8);
  };
  auto writeK = [&](int buf) {
    const int sw = (krow & 7) << 3;
    *(bf16x8*)(&Klds[buf][krow * 64 + (kd0 ^ sw)])       = kreg[0];
    *(bf16x8*)(&Klds[buf][krow * 64 + ((kd0 + 8) ^ sw)]) = kreg[1];
  };
  auto loadV = [&](int kt) {
    const short* vp = Vbase + (long)krow * L + kt * KT + kd0;
    vreg[0] = *(const bf16x8*)vp;
    vreg[1] = *(const bf16x8*)(vp + 8);
  };
  auto writeV = [&](int buf) {
    const int sw = (krow & 7) << 3;
    *(bf16x8*)(&Vlds[buf][krow * 64 + (kd0 ^ sw)])       = vreg[0];
    *(bf16x8*)(&Vlds[buf][krow * 64 + ((kd0 + 8) ^ sw)]) = vreg[1];
  };

  auto computeS2 = [&](int buf, f32x4 s0[4], f32x4 s1[4]) {
    #pragma unroll
    for (int f = 0; f < 4; ++f) {
      s0[f] = (f32x4){0.f, 0.f, 0.f, 0.f};
      s1[f] = (f32x4){0.f, 0.f, 0.f, 0.f};
      int kr = f * 16 + qr;
      #pragma unroll
      for (int c = 0; c < 2; ++c) {
        int d0c = g * 8 + 32 * c;
        bf16x8 a = *(const bf16x8*)(&Klds[buf][kr * 64 + (d0c ^ ((kr & 7) << 3))]);
        s0[f] = MFMA16(a, qfrag[0][c], s0[f]);
        s1[f] = MFMA16(a, qfrag[1][c], s1[f]);
      }
    }
  };

  f32x4 o0[4] = {{0.f,0.f,0.f,0.f},{0.f,0.f,0.f,0.f},{0.f,0.f,0.f,0.f},{0.f,0.f,0.f,0.f}};
  f32x4 o1[4] = {{0.f,0.f,0.f,0.f},{0.f,0.f,0.f,0.f},{0.f,0.f,0.f,0.f},{0.f,0.f,0.f,0.f}};
  float* ap0 = attn + (long)head * L * L + (long)(qrow0 + qr) * L;
  float* ap1 = ap0 + 16 * L;

  auto doHalf = [&](f32x4 s[4], float rinv, float* ap, f32x4 o[4], int cur, int kt) {
    #pragma unroll
    for (int f = 0; f < 4; ++f) {
      f32x4 pf;
      #pragma unroll
      for (int r = 0; r < 4; ++r)
        pf[r] = __builtin_amdgcn_exp2f(s[f][r]) * rinv;
      *(f32x4*)(ap + kt * KT + f * 16 + g * 4) = pf;
      bf16x4 p;
      #pragma unroll
      for (int r = 0; r < 4; ++r) p[r] = f2bf(pf[r]);
      int k0 = f * 16 + g * 4;
      *(bf16x4*)(&Plds[w][qr * 64 + (k0 ^ ((qr & 7) << 3))]) = p;
    }
    __builtin_amdgcn_wave_barrier();   // P writes before PV reads (wave-private)
    #pragma unroll
    for (int kc = 0; kc < 2; ++kc) {
      int k0 = kc * 32 + g * 8;
      bf16x8 pa = *(const bf16x8*)(&Plds[w][qr * 64 + (k0 ^ ((qr & 7) << 3))]);
      #pragma unroll
      for (int fr = 0; fr < 4; ++fr) {
        int d = fr * 16 + qr;
        bf16x8 vb = *(const bf16x8*)(&Vlds[cur][d * 64 + (k0 ^ ((d & 7) << 3))]);
        o[fr] = MFMA16(pa, vb, o[fr]);
      }
    }
    __builtin_amdgcn_wave_barrier();   // PV reads before next half's P writes (WAR)
  };

  loadK(0); loadV(0);
  writeK(0); writeV(0);
  sync_lds();

  for (int kt = 0; kt < NT; ++kt) {
    const int cur = kt & 1;
    if (kt + 1 < NT) { loadK(kt + 1); loadV(kt + 1); }

    f32x4 s0[4], s1[4];
    computeS2(cur, s0, s1);

    doHalf(s0, rinv0, ap0, o0, cur, kt);
    doHalf(s1, rinv1, ap1, o1, cur, kt);

    if (kt + 1 < NT) { writeK(cur ^ 1); writeV(cur ^ 1); }
    sync_lds();
  }

  float* op = out + hoff + (long)qrow0 * D;
  #pragma unroll
  for (int fr = 0; fr < 4; ++fr)
    #pragma unroll
    for (int r = 0; r < 4; ++r) {
      op[(long)(g * 4 + r) * D + fr * 16 + qr]      = o0[fr][r];
      op[(long)(16 + g * 4 + r) * D + fr * 16 + qr] = o1[fr][r];
    }
}

// ============ fallback (round-5 proven kernel, f32-staged) ============
__global__ __launch_bounds__(256, 4)
void sdpa_fused(const float* __restrict__ Q, const float* __restrict__ K,
                const float* __restrict__ V, float* __restrict__ out,
                float* __restrict__ attn)
{
  __shared__ short Klds[2][KT * D];
  __shared__ short Vlds[2][D * KT];
  __shared__ short Plds[4][16 * KT];

  const int t = threadIdx.x, lane = t & 63, w = t >> 6;
  const int qr = lane & 15, g = lane >> 4;
  const int head = blockIdx.x >> 5, qt = blockIdx.x & 31;
  const long hoff = (long)head * L * D;
  const int qrow0 = qt * 64 + w * 16;

  bf16x8 qfrag[2];
  {
    const float* qp = Q + hoff + (long)(qrow0 + qr) * D + g * 8;
    #pragma unroll
    for (int c = 0; c < 2; ++c)
      #pragma unroll
      for (int j = 0; j < 8; ++j)
        qfrag[c][j] = f2bf(qp[32 * c + j] * QSCALE);
  }

  const float* Kbase = K + hoff;
  const float* Vbase = V + hoff;
  f32x4 kreg[4], vreg[4];

  auto loadK = [&](int kt) {
    const float* kp = Kbase + (long)kt * KT * D;
    #pragma unroll
    for (int c = 0; c < 4; ++c)
      kreg[c] = *(const f32x4*)(kp + (t + 256 * c) * 4);
  };
  auto writeK = [&](int buf) {
    #pragma unroll
    for (int c = 0; c < 4; ++c) {
      int f = t + 256 * c;
      int kr = f >> 4, col = (f & 15) * 4;
      bf16x4 y;
      #pragma unroll
      for (int i = 0; i < 4; ++i) y[i] = f2bf(kreg[c][i]);
      *(bf16x4*)(&Klds[buf][kr * 64 + (col ^ ((kr & 7) << 3))]) = y;
    }
  };
  auto loadV = [&](int kt) {
    const float* vp = Vbase + (long)kt * KT * D;
    int kr0 = (t >> 4) * 4, d0 = (t & 15) * 4;
    #pragma unroll
    for (int i = 0; i < 4; ++i)
      vreg[i] = *(const f32x4*)(vp + (kr0 + i) * D + d0);
  };
  auto writeV = [&](int buf) {
    int kr0 = (t >> 4) * 4, d0 = (t & 15) * 4;
    #pragma unroll
    for (int j = 0; j < 4; ++j) {
      bf16x4 y;
      #pragma unroll
      for (int i = 0; i < 4; ++i) y[i] = f2bf(vreg[i][j]);
      int d = d0 + j;
      *(bf16x4*)(&Vlds[buf][d * 64 + (kr0 ^ ((d & 7) << 3))]) = y;
    }
  };
  auto computeS = [&](int buf, f32x4 s[4]) {
    #pragma unroll
    for (int f = 0; f < 4; ++f) {
      s[f] = (f32x4){0.f, 0.f, 0.f, 0.f};
      int kr = f * 16 + qr;
      #pragma unroll
      for (int c = 0; c < 2; ++c) {
        int d0c = g * 8 + 32 * c;
        bf16x8 a = *(const bf16x8*)(&Klds[buf][kr * 64 + (d0c ^ ((kr & 7) << 3))]);
        s[f] = MFMA16(a, qfrag[c], s[f]);
      }
    }
  };

  loadK(0); writeK(0);
  sync_lds();
  float rsum = 0.f;
  for (int kt = 0; kt < NT; ++kt) {
    const int cur = kt & 1;
    if (kt + 1 < NT) loadK(kt + 1);
    f32x4 s[4];
    computeS(cur, s);
    #pragma unroll
    for (int f = 0; f < 4; ++f)
      #pragma unroll
      for (int r = 0; r < 4; ++r)
        rsum += __builtin_amdgcn_exp2f(s[f][r]);
    if (kt + 1 < NT) writeK(cur ^ 1);
    sync_lds();
  }
  rsum += __shfl_xor(rsum, 16);
  rsum += __shfl_xor(rsum, 32);
  const float rinv = 1.f / rsum;

  f32x4 o[4] = {{0.f,0.f,0.f,0.f},{0.f,0.f,0.f,0.f},{0.f,0.f,0.f,0.f},{0.f,0.f,0.f,0.f}};
  float* ap_base = attn + (long)head * L * L + (long)qrow0 * L;

  loadK(0); loadV(0);
  writeK(0); writeV(0);
  sync_lds();

  for (int kt = 0; kt < NT; ++kt) {
    const int cur = kt & 1;
    if (kt + 1 < NT) { loadK(kt + 1); loadV(kt + 1); }

    f32x4 s[4];
    computeS(cur, s);

    #pragma unroll
    for (int f = 0; f < 4; ++f) {
      bf16x4 p;
      #pragma unroll
      for (int r = 0; r < 4; ++r)
        p[r] = f2bf(__builtin_amdgcn_exp2f(s[f][r]) * rinv);
      int k0 = f * 16 + g * 4;
      *(bf16x4*)(&Plds[w][qr * 64 + (k0 ^ ((qr & 7) << 3))]) = p;
    }
    __builtin_amdgcn_wave_barrier();

    float* ap = ap_base + (long)kt * KT;
    #pragma unroll
    for (int i = 0; i < 4; ++i) {
      int r = 4 * i + g, col = 4 * qr;
      bf16x4 pb = *(const bf16x4*)(&Plds[w][r * 64 + (col ^ ((r & 7) << 3))]);
      f32x4 pf;
      #pragma unroll
      for (int j = 0; j < 4; ++j) pf[j] = bf2f(pb[j]);
      *(f32x4*)(ap + (long)r * L + col) = pf;
    }

    #pragma unroll
    for (int kc = 0; kc < 2; ++kc) {
      int k0 = kc * 32 + g * 8;
      bf16x8 pa = *(const bf16x8*)(&Plds[w][qr * 64 + (k0 ^ ((qr & 7) << 3))]);
      #pragma unroll
      for (int fr = 0; fr < 4; ++fr) {
        int d = fr * 16 + qr;
        bf16x8 vb = *(const bf16x8*)(&Vlds[cur][d * 64 + (k0 ^ ((d & 7) << 3))]);
        o[fr] = MFMA16(pa, vb, o[fr]);
      }
    }

    if (kt + 1 < NT) { writeK(cur ^ 1); writeV(cur ^ 1); }
    sync_lds();
  }

  float* op = out + hoff + (long)qrow0 * D;
  #pragma unroll
  for (int fr = 0; fr < 4; ++fr)
    #pragma unroll
    for (int r = 0; r < 4; ++r) {
      int qq = g * 4 + r;
      op[(long)qq * D + fr * 16 + qr] = o[fr][r];
    }
}

extern "C" void kernel_launch(void* const* d_in, const int* in_sizes, int n_in,
                              void* d_out, int out_size, void* d_ws, size_t ws_size,
                              hipStream_t stream) {
  const float* q = (const float*)d_in[0];
  const float* k = (const float*)d_in[1];
  const float* v = (const float*)d_in[2];
  float* out  = (float*)d_out;                          // (B,H,L,D)
  float* attn = (float*)d_out + (size_t)NHEAD * L * D;  // (B,H,L,L)

  dim3 block(256);

  if (ws_size >= WS_NEED) {
    short* Qb   = (short*)d_ws;
    short* Kb   = Qb + BF_ELEMS;
    short* Vtb  = Kb + BF_ELEMS;
    float* rinv = (float*)(Vtb + BF_ELEMS);
    hipLaunchKernelGGL(sdpa_prepV,   dim3(NHEAD * NT),  block, 0, stream, v, Vtb);
    hipLaunchKernelGGL(sdpa_rowsum2, dim3(NHEAD * NQT), block, 0, stream, q, k, Qb, Kb, rinv);
    hipLaunchKernelGGL(sdpa_main,    dim3(NHEAD * NQT), block, 0, stream, Qb, Kb, Vtb, rinv, out, attn);
  } else {
    hipLaunchKernelGGL(sdpa_fused, dim3(NHEAD * NT), block, 0, stream, q, k, v, out, attn);
  }
}

// Round 11
// 312.010 us; speedup vs baseline: 1.3590x; 1.1528x over previous
//
#include <hip/hip_runtime.h>
#include <hip/hip_bf16.h>

typedef __attribute__((ext_vector_type(4))) float  f32x4;
typedef __attribute__((ext_vector_type(8))) short  bf16x8;
typedef __attribute__((ext_vector_type(4))) short  bf16x4;

#define MFMA16(a, b, c) __builtin_amdgcn_mfma_f32_16x16x32_bf16((a), (b), (c), 0, 0, 0)

__device__ __forceinline__ short f2bf(float f) {
  return __builtin_bit_cast(short, __float2bfloat16(f));
}
__device__ __forceinline__ float bf2f(short b) {
  return __builtin_bit_cast(float, ((unsigned)(unsigned short)b) << 16);
}

__device__ __forceinline__ void sync_lds() {
  asm volatile("s_waitcnt lgkmcnt(0)" ::: "memory");
  __builtin_amdgcn_s_barrier();
  asm volatile("" ::: "memory");
}

constexpr int L = 2048, D = 64, KT = 64, NT = L / KT;    // rowsum tiling
constexpr int KT2 = 128, NT2 = L / KT2;                  // main tiling (512B runs)
constexpr int NHEAD = 64;
constexpr int QB = 128, NQT = L / QB;                    // 16 q-tiles, 1024 items
constexpr int GRID_MAIN = 768;                           // 3 blocks/CU exact
constexpr float QSCALE = 0.18033688011112042f;           // 0.125*log2(e)
constexpr size_t BF_ELEMS = (size_t)NHEAD * L * D;
constexpr size_t WS_NEED = 3 * BF_ELEMS * sizeof(short) + (size_t)NHEAD * L * sizeof(float);

// ============ prepV: V f32 -> bf16 transposed per head ============
__global__ __launch_bounds__(256)
void sdpa_prepV(const float* __restrict__ V, short* __restrict__ Vtb)
{
  __shared__ short Tl[64 * 72];
  const int t = threadIdx.x;
  const int head = blockIdx.x >> 5, kt = blockIdx.x & 31;
  const long base = (long)head * L * D + (long)kt * 64 * D;

  const int kr0 = (t >> 4) * 4, d0 = (t & 15) * 4;
  const float* vp = V + base;
  f32x4 r[4];
  #pragma unroll
  for (int i = 0; i < 4; ++i) r[i] = *(const f32x4*)(vp + (kr0 + i) * D + d0);
  #pragma unroll
  for (int j = 0; j < 4; ++j) {
    bf16x4 y;
    #pragma unroll
    for (int i = 0; i < 4; ++i) y[i] = f2bf(r[i][j]);
    *(bf16x4*)(&Tl[(d0 + j) * 72 + kr0]) = y;
  }
  __syncthreads();
  const int d = t >> 2, k0 = (t & 3) * 16;
  bf16x8 a = *(const bf16x8*)(&Tl[d * 72 + k0]);
  bf16x8 b = *(const bf16x8*)(&Tl[d * 72 + k0 + 8]);
  short* vo = Vtb + (long)head * D * L + (long)d * L + kt * 64 + k0;
  *(bf16x8*)vo = a; *(bf16x8*)(vo + 8) = b;
}

// ===== rowsum2: f32 Q/K in; rinv out; Qb/Kb bf16 written as side effects =====
__global__ __launch_bounds__(256, 4)
void sdpa_rowsum2(const float* __restrict__ Qf, const float* __restrict__ Kf,
                  short* __restrict__ Qb, short* __restrict__ Kb,
                  float* __restrict__ rinv_out)
{
  __shared__ short Klds[2][KT * D];

  const int t = threadIdx.x, lane = t & 63, w = t >> 6;
  const int qr = lane & 15, g = lane >> 4;

  const int bid = blockIdx.x;
  const int wid = ((bid & 7) << 7) | (bid >> 3);
  const int head = wid >> 4, qt = wid & 15;
  const long hoff = (long)head * L * D;
  const int qrow0 = qt * QB + w * 32;

  // stream-convert this block's 128 Q rows -> Qb
  {
    const float* qp = Qf + hoff + (long)qt * QB * D + t * 32;
    short*       qo = Qb + hoff + (long)qt * QB * D + t * 32;
    #pragma unroll
    for (int c = 0; c < 4; ++c) {
      f32x4 a = *(const f32x4*)(qp + c * 8);
      f32x4 b = *(const f32x4*)(qp + c * 8 + 4);
      bf16x8 y;
      #pragma unroll
      for (int j = 0; j < 4; ++j) {
        y[j]     = f2bf(a[j] * QSCALE);
        y[4 + j] = f2bf(b[j] * QSCALE);
      }
      *(bf16x8*)(qo + c * 8) = y;
    }
  }

  bf16x8 qfrag[2][2];
  #pragma unroll
  for (int h = 0; h < 2; ++h)
    #pragma unroll
    for (int c = 0; c < 2; ++c) {
      const float* qp = Qf + hoff + (long)(qrow0 + 16 * h + qr) * D + g * 8 + 32 * c;
      f32x4 a = *(const f32x4*)qp;
      f32x4 b = *(const f32x4*)(qp + 4);
      #pragma unroll
      for (int j = 0; j < 4; ++j) {
        qfrag[h][c][j]     = f2bf(a[j] * QSCALE);
        qfrag[h][c][4 + j] = f2bf(b[j] * QSCALE);
      }
    }

  const float* KfH = Kf + hoff;
  short*       KbH = Kb + hoff;
  const int krow = t >> 2, kd0 = (t & 3) * 16;
  f32x4 kf[4];
  bf16x8 kb0, kb1;

  auto loadK = [&](int kt) {
    const float* kp = KfH + (long)(kt * KT + krow) * D + kd0;
    #pragma unroll
    for (int i = 0; i < 4; ++i) kf[i] = *(const f32x4*)(kp + 4 * i);
  };
  auto cvtK = [&]() {
    #pragma unroll
    for (int j = 0; j < 8; ++j) {
      kb0[j] = f2bf(kf[j >> 2][j & 3]);
      kb1[j] = f2bf(kf[2 + (j >> 2)][j & 3]);
    }
  };
  auto writeKlds = [&](int buf) {
    const int sw = (krow & 7) << 3;
    *(bf16x8*)(&Klds[buf][krow * 64 + (kd0 ^ sw)])       = kb0;
    *(bf16x8*)(&Klds[buf][krow * 64 + ((kd0 + 8) ^ sw)]) = kb1;
  };
  auto maybeWriteKb = [&](int kt) {
    if ((kt >> 1) == qt) {
      short* ko = KbH + (long)(kt * KT + krow) * D + kd0;
      *(bf16x8*)ko = kb0;
      *(bf16x8*)(ko + 8) = kb1;
    }
  };

  loadK(0); cvtK(); writeKlds(0); maybeWriteKb(0);
  sync_lds();
  float rsum0 = 0.f, rsum1 = 0.f;
  for (int kt = 0; kt < NT; ++kt) {
    const int cur = kt & 1;
    if (kt + 1 < NT) loadK(kt + 1);
    #pragma unroll
    for (int f = 0; f < 4; ++f) {
      f32x4 s0 = (f32x4){0.f,0.f,0.f,0.f};
      f32x4 s1 = (f32x4){0.f,0.f,0.f,0.f};
      int kr = f * 16 + qr;
      #pragma unroll
      for (int c = 0; c < 2; ++c) {
        int d0c = g * 8 + 32 * c;
        bf16x8 a = *(const bf16x8*)(&Klds[cur][kr * 64 + (d0c ^ ((kr & 7) << 3))]);
        s0 = MFMA16(a, qfrag[0][c], s0);
        s1 = MFMA16(a, qfrag[1][c], s1);
      }
      #pragma unroll
      for (int r = 0; r < 4; ++r) {
        rsum0 += __builtin_amdgcn_exp2f(s0[r]);
        rsum1 += __builtin_amdgcn_exp2f(s1[r]);
      }
    }
    if (kt + 1 < NT) { cvtK(); writeKlds(cur ^ 1); maybeWriteKb(kt + 1); }
    sync_lds();
  }
  rsum0 += __shfl_xor(rsum0, 16); rsum0 += __shfl_xor(rsum0, 32);
  rsum1 += __shfl_xor(rsum1, 16); rsum1 += __shfl_xor(rsum1, 32);
  if (lane < 16) {
    float* ro = rinv_out + (long)head * L + qrow0;
    ro[qr]      = 1.f / rsum0;
    ro[16 + qr] = 1.f / rsum1;
  }
}

// ========== main: KT2=128 tiles, 512B attn row-runs, 3 blocks/CU ==========
__global__ __launch_bounds__(256, 3)
void sdpa_main(const short* __restrict__ Qb, const short* __restrict__ Kb,
               const short* __restrict__ Vtb, const float* __restrict__ rinv_ws,
               float* __restrict__ out, float* __restrict__ attn)
{
  __shared__ short Klds[KT2 * D];       // [kr 128][d 64]   16 KB
  __shared__ short Vlds[D * KT2];       // [d 64][k 128]    16 KB
  __shared__ short Plds[4][16 * KT2];   // per-wave [q 16][k 128]  16 KB

  const int t = threadIdx.x, lane = t & 63, w = t >> 6;
  const int qr = lane & 15, g = lane >> 4;
  const int rlo = lane >> 5;            // attn-readback row parity

  const int krow = t >> 1, kd0 = (t & 1) * 32;   // K staging coords
  const int vd   = t >> 2, vk0 = (t & 3) * 32;   // V staging coords

  for (int item = blockIdx.x; item < NHEAD * NQT; item += GRID_MAIN) {
    const int wid = ((item & 7) << 7) | (item >> 3);   // XCD-affine, bijective
    const int head = wid >> 4, qt = wid & 15;
    const long hoff = (long)head * L * D;
    const int qrow0 = qt * QB + w * 32;

    const float rinv0 = rinv_ws[(long)head * L + qrow0 + qr];
    const float rinv1 = rinv_ws[(long)head * L + qrow0 + 16 + qr];

    bf16x8 qfrag[2][2];
    #pragma unroll
    for (int h = 0; h < 2; ++h) {
      const short* qbp = Qb + hoff + (long)(qrow0 + 16 * h + qr) * D + g * 8;
      qfrag[h][0] = *(const bf16x8*)qbp;
      qfrag[h][1] = *(const bf16x8*)(qbp + 32);
    }

    const short* Kbase = Kb + hoff;
    const short* Vbase = Vtb + (long)head * D * L;

    bf16x8 kreg[4], vreg[4];

    auto loadK = [&](int kt) {
      const short* kp = Kbase + (long)(kt * KT2 + krow) * D + kd0;
      #pragma unroll
      for (int i = 0; i < 4; ++i) kreg[i] = *(const bf16x8*)(kp + 8 * i);
    };
    auto writeK = [&]() {
      const int sw = (krow & 7) << 3;
      #pragma unroll
      for (int i = 0; i < 4; ++i)
        *(bf16x8*)(&Klds[krow * 64 + ((kd0 + 8 * i) ^ sw)]) = kreg[i];
    };
    auto loadV = [&](int kt) {
      const short* vp = Vbase + (long)vd * L + kt * KT2 + vk0;
      #pragma unroll
      for (int i = 0; i < 4; ++i) vreg[i] = *(const bf16x8*)(vp + 8 * i);
    };
    auto writeV = [&]() {
      const int sw = (vd & 7) << 3;
      #pragma unroll
      for (int i = 0; i < 4; ++i)
        *(bf16x8*)(&Vlds[vd * 128 + ((vk0 + 8 * i) ^ sw)]) = vreg[i];
    };

    f32x4 o0[4] = {{0.f,0.f,0.f,0.f},{0.f,0.f,0.f,0.f},{0.f,0.f,0.f,0.f},{0.f,0.f,0.f,0.f}};
    f32x4 o1[4] = {{0.f,0.f,0.f,0.f},{0.f,0.f,0.f,0.f},{0.f,0.f,0.f,0.f},{0.f,0.f,0.f,0.f}};
    float* apb = attn + (long)head * L * L + (long)qrow0 * L;

    // prologue: issue loads early; sync guards previous item's LDS reads
    loadK(0); loadV(0);
    sync_lds();
    writeK(); writeV();
    sync_lds();

    for (int kt = 0; kt < NT2; ++kt) {
      if (kt + 1 < NT2) { loadK(kt + 1); loadV(kt + 1); }   // reg prefetch

      #pragma unroll
      for (int h = 0; h < 2; ++h) {
        // ---- S for this q-half: 8 fragments of 16 k ----
        f32x4 s[8];
        #pragma unroll
        for (int f = 0; f < 8; ++f) {
          s[f] = (f32x4){0.f, 0.f, 0.f, 0.f};
          int kr = f * 16 + qr;
          #pragma unroll
          for (int c = 0; c < 2; ++c) {
            int d0c = g * 8 + 32 * c;
            bf16x8 a = *(const bf16x8*)(&Klds[kr * 64 + (d0c ^ ((kr & 7) << 3))]);
            s[f] = MFMA16(a, qfrag[h][c], s[f]);
          }
        }
        const float rinv = h ? rinv1 : rinv0;
        // ---- P -> Plds (bf16) ----
        #pragma unroll
        for (int f = 0; f < 8; ++f) {
          bf16x4 p;
          #pragma unroll
          for (int r = 0; r < 4; ++r)
            p[r] = f2bf(__builtin_amdgcn_exp2f(s[f][r]) * rinv);
          int k0 = f * 16 + g * 4;
          *(bf16x4*)(&Plds[w][qr * 128 + (k0 ^ ((qr & 7) << 3))]) = p;
        }
        __builtin_amdgcn_wave_barrier();   // P writes before reads (wave-private)

        // ---- attn: 2 rows x 512B contiguous per instruction ----
        {
          float* ap = apb + (long)(16 * h) * L + (long)kt * KT2;
          const int col4 = (lane & 31) * 4;
          #pragma unroll
          for (int i = 0; i < 8; ++i) {
            int r = 2 * i + rlo;
            bf16x4 pb = *(const bf16x4*)(&Plds[w][r * 128 + (col4 ^ ((r & 7) << 3))]);
            f32x4 pf;
            #pragma unroll
            for (int j = 0; j < 4; ++j) pf[j] = bf2f(pb[j]);
            *(f32x4*)(ap + (long)r * L + col4) = pf;
          }
        }

        // ---- PV: O(16q x 64d) += P(16x128) * V(128x64) ----
        #pragma unroll
        for (int kc = 0; kc < 4; ++kc) {
          int k0 = kc * 32 + g * 8;
          bf16x8 pa = *(const bf16x8*)(&Plds[w][qr * 128 + (k0 ^ ((qr & 7) << 3))]);
          #pragma unroll
          for (int fr = 0; fr < 4; ++fr) {
            int d = fr * 16 + qr;
            bf16x8 vb = *(const bf16x8*)(&Vlds[d * 128 + (k0 ^ ((d & 7) << 3))]);
            if (h == 0) o0[fr] = MFMA16(pa, vb, o0[fr]);
            else        o1[fr] = MFMA16(pa, vb, o1[fr]);
          }
        }
        __builtin_amdgcn_wave_barrier();   // PV reads before next half's P writes
      }

      sync_lds();                          // all waves done with Klds/Vlds
      if (kt + 1 < NT2) { writeK(); writeV(); sync_lds(); }
    }

    float* op = out + hoff + (long)qrow0 * D;
    #pragma unroll
    for (int fr = 0; fr < 4; ++fr)
      #pragma unroll
      for (int r = 0; r < 4; ++r) {
        op[(long)(g * 4 + r) * D + fr * 16 + qr]      = o0[fr][r];
        op[(long)(16 + g * 4 + r) * D + fr * 16 + qr] = o1[fr][r];
      }
  }
}

// ============ fallback (round-5 proven kernel, f32-staged) ============
__global__ __launch_bounds__(256, 4)
void sdpa_fused(const float* __restrict__ Q, const float* __restrict__ K,
                const float* __restrict__ V, float* __restrict__ out,
                float* __restrict__ attn)
{
  __shared__ short Klds[2][KT * D];
  __shared__ short Vlds[2][D * KT];
  __shared__ short Plds[4][16 * KT];

  const int t = threadIdx.x, lane = t & 63, w = t >> 6;
  const int qr = lane & 15, g = lane >> 4;
  const int head = blockIdx.x >> 5, qt = blockIdx.x & 31;
  const long hoff = (long)head * L * D;
  const int qrow0 = qt * 64 + w * 16;

  bf16x8 qfrag[2];
  {
    const float* qp = Q + hoff + (long)(qrow0 + qr) * D + g * 8;
    #pragma unroll
    for (int c = 0; c < 2; ++c)
      #pragma unroll
      for (int j = 0; j < 8; ++j)
        qfrag[c][j] = f2bf(qp[32 * c + j] * QSCALE);
  }

  const float* Kbase = K + hoff;
  const float* Vbase = V + hoff;
  f32x4 kreg[4], vreg[4];

  auto loadK = [&](int kt) {
    const float* kp = Kbase + (long)kt * KT * D;
    #pragma unroll
    for (int c = 0; c < 4; ++c)
      kreg[c] = *(const f32x4*)(kp + (t + 256 * c) * 4);
  };
  auto writeK = [&](int buf) {
    #pragma unroll
    for (int c = 0; c < 4; ++c) {
      int f = t + 256 * c;
      int kr = f >> 4, col = (f & 15) * 4;
      bf16x4 y;
      #pragma unroll
      for (int i = 0; i < 4; ++i) y[i] = f2bf(kreg[c][i]);
      *(bf16x4*)(&Klds[buf][kr * 64 + (col ^ ((kr & 7) << 3))]) = y;
    }
  };
  auto loadV = [&](int kt) {
    const float* vp = Vbase + (long)kt * KT * D;
    int kr0 = (t >> 4) * 4, d0 = (t & 15) * 4;
    #pragma unroll
    for (int i = 0; i < 4; ++i)
      vreg[i] = *(const f32x4*)(vp + (kr0 + i) * D + d0);
  };
  auto writeV = [&](int buf) {
    int kr0 = (t >> 4) * 4, d0 = (t & 15) * 4;
    #pragma unroll
    for (int j = 0; j < 4; ++j) {
      bf16x4 y;
      #pragma unroll
      for (int i = 0; i < 4; ++i) y[i] = f2bf(vreg[i][j]);
      int d = d0 + j;
      *(bf16x4*)(&Vlds[buf][d * 64 + (kr0 ^ ((d & 7) << 3))]) = y;
    }
  };
  auto computeS = [&](int buf, f32x4 s[4]) {
    #pragma unroll
    for (int f = 0; f < 4; ++f) {
      s[f] = (f32x4){0.f, 0.f, 0.f, 0.f};
      int kr = f * 16 + qr;
      #pragma unroll
      for (int c = 0; c < 2; ++c) {
        int d0c = g * 8 + 32 * c;
        bf16x8 a = *(const bf16x8*)(&Klds[buf][kr * 64 + (d0c ^ ((kr & 7) << 3))]);
        s[f] = MFMA16(a, qfrag[c], s[f]);
      }
    }
  };

  loadK(0); writeK(0);
  sync_lds();
  float rsum = 0.f;
  for (int kt = 0; kt < NT; ++kt) {
    const int cur = kt & 1;
    if (kt + 1 < NT) loadK(kt + 1);
    f32x4 s[4];
    computeS(cur, s);
    #pragma unroll
    for (int f = 0; f < 4; ++f)
      #pragma unroll
      for (int r = 0; r < 4; ++r)
        rsum += __builtin_amdgcn_exp2f(s[f][r]);
    if (kt + 1 < NT) writeK(cur ^ 1);
    sync_lds();
  }
  rsum += __shfl_xor(rsum, 16);
  rsum += __shfl_xor(rsum, 32);
  const float rinv = 1.f / rsum;

  f32x4 o[4] = {{0.f,0.f,0.f,0.f},{0.f,0.f,0.f,0.f},{0.f,0.f,0.f,0.f},{0.f,0.f,0.f,0.f}};
  float* ap_base = attn + (long)head * L * L + (long)qrow0 * L;

  loadK(0); loadV(0);
  writeK(0); writeV(0);
  sync_lds();

  for (int kt = 0; kt < NT; ++kt) {
    const int cur = kt & 1;
    if (kt + 1 < NT) { loadK(kt + 1); loadV(kt + 1); }

    f32x4 s[4];
    computeS(cur, s);

    #pragma unroll
    for (int f = 0; f < 4; ++f) {
      bf16x4 p;
      #pragma unroll
      for (int r = 0; r < 4; ++r)
        p[r] = f2bf(__builtin_amdgcn_exp2f(s[f][r]) * rinv);
      int k0 = f * 16 + g * 4;
      *(bf16x4*)(&Plds[w][qr * 64 + (k0 ^ ((qr & 7) << 3))]) = p;
    }
    __builtin_amdgcn_wave_barrier();

    float* ap = ap_base + (long)kt * KT;
    #pragma unroll
    for (int i = 0; i < 4; ++i) {
      int r = 4 * i + g, col = 4 * qr;
      bf16x4 pb = *(const bf16x4*)(&Plds[w][r * 64 + (col ^ ((r & 7) << 3))]);
      f32x4 pf;
      #pragma unroll
      for (int j = 0; j < 4; ++j) pf[j] = bf2f(pb[j]);
      *(f32x4*)(ap + (long)r * L + col) = pf;
    }

    #pragma unroll
    for (int kc = 0; kc < 2; ++kc) {
      int k0 = kc * 32 + g * 8;
      bf16x8 pa = *(const bf16x8*)(&Plds[w][qr * 64 + (k0 ^ ((qr & 7) << 3))]);
      #pragma unroll
      for (int fr = 0; fr < 4; ++fr) {
        int d = fr * 16 + qr;
        bf16x8 vb = *(const bf16x8*)(&Vlds[cur][d * 64 + (k0 ^ ((d & 7) << 3))]);
        o[fr] = MFMA16(pa, vb, o[fr]);
      }
    }

    if (kt + 1 < NT) { writeK(cur ^ 1); writeV(cur ^ 1); }
    sync_lds();
  }

  float* op = out + hoff + (long)qrow0 * D;
  #pragma unroll
  for (int fr = 0; fr < 4; ++fr)
    #pragma unroll
    for (int r = 0; r < 4; ++r) {
      int qq = g * 4 + r;
      op[(long)qq * D + fr * 16 + qr] = o[fr][r];
    }
}

extern "C" void kernel_launch(void* const* d_in, const int* in_sizes, int n_in,
                              void* d_out, int out_size, void* d_ws, size_t ws_size,
                              hipStream_t stream) {
  const float* q = (const float*)d_in[0];
  const float* k = (const float*)d_in[1];
  const float* v = (const float*)d_in[2];
  float* out  = (float*)d_out;                          // (B,H,L,D)
  float* attn = (float*)d_out + (size_t)NHEAD * L * D;  // (B,H,L,L)

  dim3 block(256);

  if (ws_size >= WS_NEED) {
    short* Qb   = (short*)d_ws;
    short* Kb   = Qb + BF_ELEMS;
    short* Vtb  = Kb + BF_ELEMS;
    float* rinv = (float*)(Vtb + BF_ELEMS);
    hipLaunchKernelGGL(sdpa_prepV,   dim3(NHEAD * NT),  block, 0, stream, v, Vtb);
    hipLaunchKernelGGL(sdpa_rowsum2, dim3(NHEAD * NQT), block, 0, stream, q, k, Qb, Kb, rinv);
    hipLaunchKernelGGL(sdpa_main,    dim3(GRID_MAIN),   block, 0, stream, Qb, Kb, Vtb, rinv, out, attn);
  } else {
    hipLaunchKernelGGL(sdpa_fused, dim3(NHEAD * NT), block, 0, stream, q, k, v, out, attn);
  }
}

// Round 12
// 309.302 us; speedup vs baseline: 1.3708x; 1.0088x over previous
//
#include <hip/hip_runtime.h>
#include <hip/hip_bf16.h>

typedef __attribute__((ext_vector_type(4))) float  f32x4;
typedef __attribute__((ext_vector_type(8))) short  bf16x8;
typedef __attribute__((ext_vector_type(4))) short  bf16x4;

#define MFMA16(a, b, c) __builtin_amdgcn_mfma_f32_16x16x32_bf16((a), (b), (c), 0, 0, 0)

__device__ __forceinline__ short f2bf(float f) {
  return __builtin_bit_cast(short, __float2bfloat16(f));
}
__device__ __forceinline__ float bf2f(short b) {
  return __builtin_bit_cast(float, ((unsigned)(unsigned short)b) << 16);
}

__device__ __forceinline__ void sync_lds() {
  asm volatile("s_waitcnt lgkmcnt(0)" ::: "memory");
  __builtin_amdgcn_s_barrier();
  asm volatile("" ::: "memory");
}

constexpr int L = 2048, D = 64, KT = 64, NT = L / KT;    // rowsum tiling
constexpr int KT2 = 128, NT2 = L / KT2;                  // main tiling (512B runs)
constexpr int NHEAD = 64;
constexpr int QB = 128, NQT = L / QB;                    // 16 q-tiles, 1024 items
constexpr int GRID_MAIN = 512;                           // 2 blocks/CU, 2 items each: balanced
constexpr float QSCALE = 0.18033688011112042f;           // 0.125*log2(e)
constexpr size_t BF_ELEMS = (size_t)NHEAD * L * D;
constexpr size_t WS_NEED = 3 * BF_ELEMS * sizeof(short) + (size_t)NHEAD * L * sizeof(float);

// ============ prepV: V f32 -> bf16 transposed per head ============
__global__ __launch_bounds__(256)
void sdpa_prepV(const float* __restrict__ V, short* __restrict__ Vtb)
{
  __shared__ short Tl[64 * 72];
  const int t = threadIdx.x;
  const int head = blockIdx.x >> 5, kt = blockIdx.x & 31;
  const long base = (long)head * L * D + (long)kt * 64 * D;

  const int kr0 = (t >> 4) * 4, d0 = (t & 15) * 4;
  const float* vp = V + base;
  f32x4 r[4];
  #pragma unroll
  for (int i = 0; i < 4; ++i) r[i] = *(const f32x4*)(vp + (kr0 + i) * D + d0);
  #pragma unroll
  for (int j = 0; j < 4; ++j) {
    bf16x4 y;
    #pragma unroll
    for (int i = 0; i < 4; ++i) y[i] = f2bf(r[i][j]);
    *(bf16x4*)(&Tl[(d0 + j) * 72 + kr0]) = y;
  }
  __syncthreads();
  const int d = t >> 2, k0 = (t & 3) * 16;
  bf16x8 a = *(const bf16x8*)(&Tl[d * 72 + k0]);
  bf16x8 b = *(const bf16x8*)(&Tl[d * 72 + k0 + 8]);
  short* vo = Vtb + (long)head * D * L + (long)d * L + kt * 64 + k0;
  *(bf16x8*)vo = a; *(bf16x8*)(vo + 8) = b;
}

// ===== rowsum2: f32 Q/K in; rinv out; Qb/Kb bf16 written as side effects =====
__global__ __launch_bounds__(256, 4)
void sdpa_rowsum2(const float* __restrict__ Qf, const float* __restrict__ Kf,
                  short* __restrict__ Qb, short* __restrict__ Kb,
                  float* __restrict__ rinv_out)
{
  __shared__ short Klds[2][KT * D];

  const int t = threadIdx.x, lane = t & 63, w = t >> 6;
  const int qr = lane & 15, g = lane >> 4;

  const int bid = blockIdx.x;
  const int wid = ((bid & 7) << 7) | (bid >> 3);
  const int head = wid >> 4, qt = wid & 15;
  const long hoff = (long)head * L * D;
  const int qrow0 = qt * QB + w * 32;

  // stream-convert this block's 128 Q rows -> Qb
  {
    const float* qp = Qf + hoff + (long)qt * QB * D + t * 32;
    short*       qo = Qb + hoff + (long)qt * QB * D + t * 32;
    #pragma unroll
    for (int c = 0; c < 4; ++c) {
      f32x4 a = *(const f32x4*)(qp + c * 8);
      f32x4 b = *(const f32x4*)(qp + c * 8 + 4);
      bf16x8 y;
      #pragma unroll
      for (int j = 0; j < 4; ++j) {
        y[j]     = f2bf(a[j] * QSCALE);
        y[4 + j] = f2bf(b[j] * QSCALE);
      }
      *(bf16x8*)(qo + c * 8) = y;
    }
  }

  bf16x8 qfrag[2][2];
  #pragma unroll
  for (int h = 0; h < 2; ++h)
    #pragma unroll
    for (int c = 0; c < 2; ++c) {
      const float* qp = Qf + hoff + (long)(qrow0 + 16 * h + qr) * D + g * 8 + 32 * c;
      f32x4 a = *(const f32x4*)qp;
      f32x4 b = *(const f32x4*)(qp + 4);
      #pragma unroll
      for (int j = 0; j < 4; ++j) {
        qfrag[h][c][j]     = f2bf(a[j] * QSCALE);
        qfrag[h][c][4 + j] = f2bf(b[j] * QSCALE);
      }
    }

  const float* KfH = Kf + hoff;
  short*       KbH = Kb + hoff;
  const int krow = t >> 2, kd0 = (t & 3) * 16;
  f32x4 kf[4];
  bf16x8 kb0, kb1;

  auto loadK = [&](int kt) {
    const float* kp = KfH + (long)(kt * KT + krow) * D + kd0;
    #pragma unroll
    for (int i = 0; i < 4; ++i) kf[i] = *(const f32x4*)(kp + 4 * i);
  };
  auto cvtK = [&]() {
    #pragma unroll
    for (int j = 0; j < 8; ++j) {
      kb0[j] = f2bf(kf[j >> 2][j & 3]);
      kb1[j] = f2bf(kf[2 + (j >> 2)][j & 3]);
    }
  };
  auto writeKlds = [&](int buf) {
    const int sw = (krow & 7) << 3;
    *(bf16x8*)(&Klds[buf][krow * 64 + (kd0 ^ sw)])       = kb0;
    *(bf16x8*)(&Klds[buf][krow * 64 + ((kd0 + 8) ^ sw)]) = kb1;
  };
  auto maybeWriteKb = [&](int kt) {
    if ((kt >> 1) == qt) {
      short* ko = KbH + (long)(kt * KT + krow) * D + kd0;
      *(bf16x8*)ko = kb0;
      *(bf16x8*)(ko + 8) = kb1;
    }
  };

  loadK(0); cvtK(); writeKlds(0); maybeWriteKb(0);
  sync_lds();
  float rsum0 = 0.f, rsum1 = 0.f;
  for (int kt = 0; kt < NT; ++kt) {
    const int cur = kt & 1;
    if (kt + 1 < NT) loadK(kt + 1);
    #pragma unroll
    for (int f = 0; f < 4; ++f) {
      f32x4 s0 = (f32x4){0.f,0.f,0.f,0.f};
      f32x4 s1 = (f32x4){0.f,0.f,0.f,0.f};
      int kr = f * 16 + qr;
      #pragma unroll
      for (int c = 0; c < 2; ++c) {
        int d0c = g * 8 + 32 * c;
        bf16x8 a = *(const bf16x8*)(&Klds[cur][kr * 64 + (d0c ^ ((kr & 7) << 3))]);
        s0 = MFMA16(a, qfrag[0][c], s0);
        s1 = MFMA16(a, qfrag[1][c], s1);
      }
      #pragma unroll
      for (int r = 0; r < 4; ++r) {
        rsum0 += __builtin_amdgcn_exp2f(s0[r]);
        rsum1 += __builtin_amdgcn_exp2f(s1[r]);
      }
    }
    if (kt + 1 < NT) { cvtK(); writeKlds(cur ^ 1); maybeWriteKb(kt + 1); }
    sync_lds();
  }
  rsum0 += __shfl_xor(rsum0, 16); rsum0 += __shfl_xor(rsum0, 32);
  rsum1 += __shfl_xor(rsum1, 16); rsum1 += __shfl_xor(rsum1, 32);
  if (lane < 16) {
    float* ro = rinv_out + (long)head * L + qrow0;
    ro[qr]      = 1.f / rsum0;
    ro[16 + qr] = 1.f / rsum1;
  }
}

// ========== main: KT2=128 tiles, 512B attn row-runs, 2 blocks/CU balanced ==========
__global__ __launch_bounds__(256, 2)
void sdpa_main(const short* __restrict__ Qb, const short* __restrict__ Kb,
               const short* __restrict__ Vtb, const float* __restrict__ rinv_ws,
               float* __restrict__ out, float* __restrict__ attn)
{
  __shared__ short Klds[KT2 * D];       // [kr 128][d 64]   16 KB
  __shared__ short Vlds[D * KT2];       // [d 64][k 128]    16 KB
  __shared__ short Plds[4][16 * KT2];   // per-wave [q 16][k 128]  16 KB

  const int t = threadIdx.x, lane = t & 63, w = t >> 6;
  const int qr = lane & 15, g = lane >> 4;
  const int rlo = lane >> 5;            // attn-readback row parity

  const int krow = t >> 1, kd0 = (t & 1) * 32;   // K staging coords
  const int vd   = t >> 2, vk0 = (t & 3) * 32;   // V staging coords

  for (int item = blockIdx.x; item < NHEAD * NQT; item += GRID_MAIN) {
    const int wid = ((item & 7) << 7) | (item >> 3);   // XCD-affine, bijective
    const int head = wid >> 4, qt = wid & 15;
    const long hoff = (long)head * L * D;
    const int qrow0 = qt * QB + w * 32;

    const float rinv0 = rinv_ws[(long)head * L + qrow0 + qr];
    const float rinv1 = rinv_ws[(long)head * L + qrow0 + 16 + qr];

    bf16x8 qfrag[2][2];
    #pragma unroll
    for (int h = 0; h < 2; ++h) {
      const short* qbp = Qb + hoff + (long)(qrow0 + 16 * h + qr) * D + g * 8;
      qfrag[h][0] = *(const bf16x8*)qbp;
      qfrag[h][1] = *(const bf16x8*)(qbp + 32);
    }

    const short* Kbase = Kb + hoff;
    const short* Vbase = Vtb + (long)head * D * L;

    bf16x8 kreg[4], vreg[4];

    auto loadK = [&](int kt) {
      const short* kp = Kbase + (long)(kt * KT2 + krow) * D + kd0;
      #pragma unroll
      for (int i = 0; i < 4; ++i) kreg[i] = *(const bf16x8*)(kp + 8 * i);
    };
    auto writeK = [&]() {
      const int sw = (krow & 7) << 3;
      #pragma unroll
      for (int i = 0; i < 4; ++i)
        *(bf16x8*)(&Klds[krow * 64 + ((kd0 + 8 * i) ^ sw)]) = kreg[i];
    };
    auto loadV = [&](int kt) {
      const short* vp = Vbase + (long)vd * L + kt * KT2 + vk0;
      #pragma unroll
      for (int i = 0; i < 4; ++i) vreg[i] = *(const bf16x8*)(vp + 8 * i);
    };
    auto writeV = [&]() {
      const int sw = (vd & 7) << 3;
      #pragma unroll
      for (int i = 0; i < 4; ++i)
        *(bf16x8*)(&Vlds[vd * 128 + ((vk0 + 8 * i) ^ sw)]) = vreg[i];
    };

    f32x4 o0[4] = {{0.f,0.f,0.f,0.f},{0.f,0.f,0.f,0.f},{0.f,0.f,0.f,0.f},{0.f,0.f,0.f,0.f}};
    f32x4 o1[4] = {{0.f,0.f,0.f,0.f},{0.f,0.f,0.f,0.f},{0.f,0.f,0.f,0.f},{0.f,0.f,0.f,0.f}};
    float* apb = attn + (long)head * L * L + (long)qrow0 * L;

    // prologue: issue loads early; sync guards previous item's LDS reads
    loadK(0); loadV(0);
    sync_lds();
    writeK(); writeV();
    sync_lds();

    for (int kt = 0; kt < NT2; ++kt) {
      if (kt + 1 < NT2) { loadK(kt + 1); loadV(kt + 1); }   // reg prefetch

      #pragma unroll
      for (int h = 0; h < 2; ++h) {
        // ---- S for this q-half: 8 fragments of 16 k ----
        f32x4 s[8];
        #pragma unroll
        for (int f = 0; f < 8; ++f) {
          s[f] = (f32x4){0.f, 0.f, 0.f, 0.f};
          int kr = f * 16 + qr;
          #pragma unroll
          for (int c = 0; c < 2; ++c) {
            int d0c = g * 8 + 32 * c;
            bf16x8 a = *(const bf16x8*)(&Klds[kr * 64 + (d0c ^ ((kr & 7) << 3))]);
            s[f] = MFMA16(a, qfrag[h][c], s[f]);
          }
        }
        const float rinv = h ? rinv1 : rinv0;
        // ---- P -> Plds (bf16) ----
        #pragma unroll
        for (int f = 0; f < 8; ++f) {
          bf16x4 p;
          #pragma unroll
          for (int r = 0; r < 4; ++r)
            p[r] = f2bf(__builtin_amdgcn_exp2f(s[f][r]) * rinv);
          int k0 = f * 16 + g * 4;
          *(bf16x4*)(&Plds[w][qr * 128 + (k0 ^ ((qr & 7) << 3))]) = p;
        }
        __builtin_amdgcn_wave_barrier();   // P writes before reads (wave-private)

        // ---- attn: 2 rows x 512B contiguous per instruction ----
        {
          float* ap = apb + (long)(16 * h) * L + (long)kt * KT2;
          const int col4 = (lane & 31) * 4;
          #pragma unroll
          for (int i = 0; i < 8; ++i) {
            int r = 2 * i + rlo;
            bf16x4 pb = *(const bf16x4*)(&Plds[w][r * 128 + (col4 ^ ((r & 7) << 3))]);
            f32x4 pf;
            #pragma unroll
            for (int j = 0; j < 4; ++j) pf[j] = bf2f(pb[j]);
            *(f32x4*)(ap + (long)r * L + col4) = pf;
          }
        }

        // ---- PV: O(16q x 64d) += P(16x128) * V(128x64) ----
        #pragma unroll
        for (int kc = 0; kc < 4; ++kc) {
          int k0 = kc * 32 + g * 8;
          bf16x8 pa = *(const bf16x8*)(&Plds[w][qr * 128 + (k0 ^ ((qr & 7) << 3))]);
          #pragma unroll
          for (int fr = 0; fr < 4; ++fr) {
            int d = fr * 16 + qr;
            bf16x8 vb = *(const bf16x8*)(&Vlds[d * 128 + (k0 ^ ((d & 7) << 3))]);
            if (h == 0) o0[fr] = MFMA16(pa, vb, o0[fr]);
            else        o1[fr] = MFMA16(pa, vb, o1[fr]);
          }
        }
        __builtin_amdgcn_wave_barrier();   // PV reads before next half's P writes
      }

      sync_lds();                          // all waves done with Klds/Vlds
      if (kt + 1 < NT2) { writeK(); writeV(); sync_lds(); }
    }

    float* op = out + hoff + (long)qrow0 * D;
    #pragma unroll
    for (int fr = 0; fr < 4; ++fr)
      #pragma unroll
      for (int r = 0; r < 4; ++r) {
        op[(long)(g * 4 + r) * D + fr * 16 + qr]      = o0[fr][r];
        op[(long)(16 + g * 4 + r) * D + fr * 16 + qr] = o1[fr][r];
      }
  }
}

// ============ fallback (round-5 proven kernel, f32-staged) ============
__global__ __launch_bounds__(256, 4)
void sdpa_fused(const float* __restrict__ Q, const float* __restrict__ K,
                const float* __restrict__ V, float* __restrict__ out,
                float* __restrict__ attn)
{
  __shared__ short Klds[2][KT * D];
  __shared__ short Vlds[2][D * KT];
  __shared__ short Plds[4][16 * KT];

  const int t = threadIdx.x, lane = t & 63, w = t >> 6;
  const int qr = lane & 15, g = lane >> 4;
  const int head = blockIdx.x >> 5, qt = blockIdx.x & 31;
  const long hoff = (long)head * L * D;
  const int qrow0 = qt * 64 + w * 16;

  bf16x8 qfrag[2];
  {
    const float* qp = Q + hoff + (long)(qrow0 + qr) * D + g * 8;
    #pragma unroll
    for (int c = 0; c < 2; ++c)
      #pragma unroll
      for (int j = 0; j < 8; ++j)
        qfrag[c][j] = f2bf(qp[32 * c + j] * QSCALE);
  }

  const float* Kbase = K + hoff;
  const float* Vbase = V + hoff;
  f32x4 kreg[4], vreg[4];

  auto loadK = [&](int kt) {
    const float* kp = Kbase + (long)kt * KT * D;
    #pragma unroll
    for (int c = 0; c < 4; ++c)
      kreg[c] = *(const f32x4*)(kp + (t + 256 * c) * 4);
  };
  auto writeK = [&](int buf) {
    #pragma unroll
    for (int c = 0; c < 4; ++c) {
      int f = t + 256 * c;
      int kr = f >> 4, col = (f & 15) * 4;
      bf16x4 y;
      #pragma unroll
      for (int i = 0; i < 4; ++i) y[i] = f2bf(kreg[c][i]);
      *(bf16x4*)(&Klds[buf][kr * 64 + (col ^ ((kr & 7) << 3))]) = y;
    }
  };
  auto loadV = [&](int kt) {
    const float* vp = Vbase + (long)kt * KT * D;
    int kr0 = (t >> 4) * 4, d0 = (t & 15) * 4;
    #pragma unroll
    for (int i = 0; i < 4; ++i)
      vreg[i] = *(const f32x4*)(vp + (kr0 + i) * D + d0);
  };
  auto writeV = [&](int buf) {
    int kr0 = (t >> 4) * 4, d0 = (t & 15) * 4;
    #pragma unroll
    for (int j = 0; j < 4; ++j) {
      bf16x4 y;
      #pragma unroll
      for (int i = 0; i < 4; ++i) y[i] = f2bf(vreg[i][j]);
      int d = d0 + j;
      *(bf16x4*)(&Vlds[buf][d * 64 + (kr0 ^ ((d & 7) << 3))]) = y;
    }
  };
  auto computeS = [&](int buf, f32x4 s[4]) {
    #pragma unroll
    for (int f = 0; f < 4; ++f) {
      s[f] = (f32x4){0.f, 0.f, 0.f, 0.f};
      int kr = f * 16 + qr;
      #pragma unroll
      for (int c = 0; c < 2; ++c) {
        int d0c = g * 8 + 32 * c;
        bf16x8 a = *(const bf16x8*)(&Klds[buf][kr * 64 + (d0c ^ ((kr & 7) << 3))]);
        s[f] = MFMA16(a, qfrag[c], s[f]);
      }
    }
  };

  loadK(0); writeK(0);
  sync_lds();
  float rsum = 0.f;
  for (int kt = 0; kt < NT; ++kt) {
    const int cur = kt & 1;
    if (kt + 1 < NT) loadK(kt + 1);
    f32x4 s[4];
    computeS(cur, s);
    #pragma unroll
    for (int f = 0; f < 4; ++f)
      #pragma unroll
      for (int r = 0; r < 4; ++r)
        rsum += __builtin_amdgcn_exp2f(s[f][r]);
    if (kt + 1 < NT) writeK(cur ^ 1);
    sync_lds();
  }
  rsum += __shfl_xor(rsum, 16);
  rsum += __shfl_xor(rsum, 32);
  const float rinv = 1.f / rsum;

  f32x4 o[4] = {{0.f,0.f,0.f,0.f},{0.f,0.f,0.f,0.f},{0.f,0.f,0.f,0.f},{0.f,0.f,0.f,0.f}};
  float* ap_base = attn + (long)head * L * L + (long)qrow0 * L;

  loadK(0); loadV(0);
  writeK(0); writeV(0);
  sync_lds();

  for (int kt = 0; kt < NT; ++kt) {
    const int cur = kt & 1;
    if (kt + 1 < NT) { loadK(kt + 1); loadV(kt + 1); }

    f32x4 s[4];
    computeS(cur, s);

    #pragma unroll
    for (int f = 0; f < 4; ++f) {
      bf16x4 p;
      #pragma unroll
      for (int r = 0; r < 4; ++r)
        p[r] = f2bf(__builtin_amdgcn_exp2f(s[f][r]) * rinv);
      int k0 = f * 16 + g * 4;
      *(bf16x4*)(&Plds[w][qr * 64 + (k0 ^ ((qr & 7) << 3))]) = p;
    }
    __builtin_amdgcn_wave_barrier();

    float* ap = ap_base + (long)kt * KT;
    #pragma unroll
    for (int i = 0; i < 4; ++i) {
      int r = 4 * i + g, col = 4 * qr;
      bf16x4 pb = *(const bf16x4*)(&Plds[w][r * 64 + (col ^ ((r & 7) << 3))]);
      f32x4 pf;
      #pragma unroll
      for (int j = 0; j < 4; ++j) pf[j] = bf2f(pb[j]);
      *(f32x4*)(ap + (long)r * L + col) = pf;
    }

    #pragma unroll
    for (int kc = 0; kc < 2; ++kc) {
      int k0 = kc * 32 + g * 8;
      bf16x8 pa = *(const bf16x8*)(&Plds[w][qr * 64 + (k0 ^ ((qr & 7) << 3))]);
      #pragma unroll
      for (int fr = 0; fr < 4; ++fr) {
        int d = fr * 16 + qr;
        bf16x8 vb = *(const bf16x8*)(&Vlds[cur][d * 64 + (k0 ^ ((d & 7) << 3))]);
        o[fr] = MFMA16(pa, vb, o[fr]);
      }
    }

    if (kt + 1 < NT) { writeK(cur ^ 1); writeV(cur ^ 1); }
    sync_lds();
  }

  float* op = out + hoff + (long)qrow0 * D;
  #pragma unroll
  for (int fr = 0; fr < 4; ++fr)
    #pragma unroll
    for (int r = 0; r < 4; ++r) {
      int qq = g * 4 + r;
      op[(long)qq * D + fr * 16 + qr] = o[fr][r];
    }
}

extern "C" void kernel_launch(void* const* d_in, const int* in_sizes, int n_in,
                              void* d_out, int out_size, void* d_ws, size_t ws_size,
                              hipStream_t stream) {
  const float* q = (const float*)d_in[0];
  const float* k = (const float*)d_in[1];
  const float* v = (const float*)d_in[2];
  float* out  = (float*)d_out;                          // (B,H,L,D)
  float* attn = (float*)d_out + (size_t)NHEAD * L * D;  // (B,H,L,L)

  dim3 block(256);

  if (ws_size >= WS_NEED) {
    short* Qb   = (short*)d_ws;
    short* Kb   = Qb + BF_ELEMS;
    short* Vtb  = Kb + BF_ELEMS;
    float* rinv = (float*)(Vtb + BF_ELEMS);
    hipLaunchKernelGGL(sdpa_prepV,   dim3(NHEAD * NT),  block, 0, stream, v, Vtb);
    hipLaunchKernelGGL(sdpa_rowsum2, dim3(NHEAD * NQT), block, 0, stream, q, k, Qb, Kb, rinv);
    hipLaunchKernelGGL(sdpa_main,    dim3(GRID_MAIN),   block, 0, stream, Qb, Kb, Vtb, rinv, out, attn);
  } else {
    hipLaunchKernelGGL(sdpa_fused, dim3(NHEAD * NT), block, 0, stream, q, k, v, out, attn);
  }
}

// Round 13
// 305.212 us; speedup vs baseline: 1.3892x; 1.0134x over previous
//
#include <hip/hip_runtime.h>
#include <hip/hip_bf16.h>

typedef __attribute__((ext_vector_type(4))) float  f32x4;
typedef __attribute__((ext_vector_type(8))) short  bf16x8;
typedef __attribute__((ext_vector_type(4))) short  bf16x4;

#define MFMA16(a, b, c) __builtin_amdgcn_mfma_f32_16x16x32_bf16((a), (b), (c), 0, 0, 0)

__device__ __forceinline__ short f2bf(float f) {
  return __builtin_bit_cast(short, __float2bfloat16(f));
}
__device__ __forceinline__ float bf2f(short b) {
  return __builtin_bit_cast(float, ((unsigned)(unsigned short)b) << 16);
}

__device__ __forceinline__ void sync_lds() {
  asm volatile("s_waitcnt lgkmcnt(0)" ::: "memory");
  __builtin_amdgcn_s_barrier();
  asm volatile("" ::: "memory");
}

constexpr int L = 2048, D = 64, KT = 64, NT = L / KT;    // rowsum tiling
constexpr int KT3 = 256, NT3 = L / KT3;                  // main macro-tiles (1KB runs)
constexpr int NHEAD = 64;
constexpr int QB = 128, NQT = L / QB;                    // rowsum q-tiles (grid 1024)
constexpr int QB3 = 256, NQT3 = L / QB3;                 // main q-tiles: 512 items
constexpr int GRID_MAIN = 256;                           // 1 block/CU, 2 items each
constexpr float QSCALE = 0.18033688011112042f;           // 0.125*log2(e)
constexpr size_t BF_ELEMS = (size_t)NHEAD * L * D;
constexpr size_t WS_NEED = 3 * BF_ELEMS * sizeof(short) + (size_t)NHEAD * L * sizeof(float);

// ============ prepV: V f32 -> bf16 transposed per head ============
__global__ __launch_bounds__(256)
void sdpa_prepV(const float* __restrict__ V, short* __restrict__ Vtb)
{
  __shared__ short Tl[64 * 72];
  const int t = threadIdx.x;
  const int head = blockIdx.x >> 5, kt = blockIdx.x & 31;
  const long base = (long)head * L * D + (long)kt * 64 * D;

  const int kr0 = (t >> 4) * 4, d0 = (t & 15) * 4;
  const float* vp = V + base;
  f32x4 r[4];
  #pragma unroll
  for (int i = 0; i < 4; ++i) r[i] = *(const f32x4*)(vp + (kr0 + i) * D + d0);
  #pragma unroll
  for (int j = 0; j < 4; ++j) {
    bf16x4 y;
    #pragma unroll
    for (int i = 0; i < 4; ++i) y[i] = f2bf(r[i][j]);
    *(bf16x4*)(&Tl[(d0 + j) * 72 + kr0]) = y;
  }
  __syncthreads();
  const int d = t >> 2, k0 = (t & 3) * 16;
  bf16x8 a = *(const bf16x8*)(&Tl[d * 72 + k0]);
  bf16x8 b = *(const bf16x8*)(&Tl[d * 72 + k0 + 8]);
  short* vo = Vtb + (long)head * D * L + (long)d * L + kt * 64 + k0;
  *(bf16x8*)vo = a; *(bf16x8*)(vo + 8) = b;
}

// ===== rowsum2: f32 Q/K in; rinv out; Qb/Kb bf16 written as side effects =====
__global__ __launch_bounds__(256, 4)
void sdpa_rowsum2(const float* __restrict__ Qf, const float* __restrict__ Kf,
                  short* __restrict__ Qb, short* __restrict__ Kb,
                  float* __restrict__ rinv_out)
{
  __shared__ short Klds[2][KT * D];

  const int t = threadIdx.x, lane = t & 63, w = t >> 6;
  const int qr = lane & 15, g = lane >> 4;

  const int bid = blockIdx.x;
  const int wid = ((bid & 7) << 7) | (bid >> 3);
  const int head = wid >> 4, qt = wid & 15;
  const long hoff = (long)head * L * D;
  const int qrow0 = qt * QB + w * 32;

  // stream-convert this block's 128 Q rows -> Qb
  {
    const float* qp = Qf + hoff + (long)qt * QB * D + t * 32;
    short*       qo = Qb + hoff + (long)qt * QB * D + t * 32;
    #pragma unroll
    for (int c = 0; c < 4; ++c) {
      f32x4 a = *(const f32x4*)(qp + c * 8);
      f32x4 b = *(const f32x4*)(qp + c * 8 + 4);
      bf16x8 y;
      #pragma unroll
      for (int j = 0; j < 4; ++j) {
        y[j]     = f2bf(a[j] * QSCALE);
        y[4 + j] = f2bf(b[j] * QSCALE);
      }
      *(bf16x8*)(qo + c * 8) = y;
    }
  }

  bf16x8 qfrag[2][2];
  #pragma unroll
  for (int h = 0; h < 2; ++h)
    #pragma unroll
    for (int c = 0; c < 2; ++c) {
      const float* qp = Qf + hoff + (long)(qrow0 + 16 * h + qr) * D + g * 8 + 32 * c;
      f32x4 a = *(const f32x4*)qp;
      f32x4 b = *(const f32x4*)(qp + 4);
      #pragma unroll
      for (int j = 0; j < 4; ++j) {
        qfrag[h][c][j]     = f2bf(a[j] * QSCALE);
        qfrag[h][c][4 + j] = f2bf(b[j] * QSCALE);
      }
    }

  const float* KfH = Kf + hoff;
  short*       KbH = Kb + hoff;
  const int krow = t >> 2, kd0 = (t & 3) * 16;
  f32x4 kf[4];
  bf16x8 kb0, kb1;

  auto loadK = [&](int kt) {
    const float* kp = KfH + (long)(kt * KT + krow) * D + kd0;
    #pragma unroll
    for (int i = 0; i < 4; ++i) kf[i] = *(const f32x4*)(kp + 4 * i);
  };
  auto cvtK = [&]() {
    #pragma unroll
    for (int j = 0; j < 8; ++j) {
      kb0[j] = f2bf(kf[j >> 2][j & 3]);
      kb1[j] = f2bf(kf[2 + (j >> 2)][j & 3]);
    }
  };
  auto writeKlds = [&](int buf) {
    const int sw = (krow & 7) << 3;
    *(bf16x8*)(&Klds[buf][krow * 64 + (kd0 ^ sw)])       = kb0;
    *(bf16x8*)(&Klds[buf][krow * 64 + ((kd0 + 8) ^ sw)]) = kb1;
  };
  auto maybeWriteKb = [&](int kt) {
    if ((kt >> 1) == qt) {
      short* ko = KbH + (long)(kt * KT + krow) * D + kd0;
      *(bf16x8*)ko = kb0;
      *(bf16x8*)(ko + 8) = kb1;
    }
  };

  loadK(0); cvtK(); writeKlds(0); maybeWriteKb(0);
  sync_lds();
  float rsum0 = 0.f, rsum1 = 0.f;
  for (int kt = 0; kt < NT; ++kt) {
    const int cur = kt & 1;
    if (kt + 1 < NT) loadK(kt + 1);
    #pragma unroll
    for (int f = 0; f < 4; ++f) {
      f32x4 s0 = (f32x4){0.f,0.f,0.f,0.f};
      f32x4 s1 = (f32x4){0.f,0.f,0.f,0.f};
      int kr = f * 16 + qr;
      #pragma unroll
      for (int c = 0; c < 2; ++c) {
        int d0c = g * 8 + 32 * c;
        bf16x8 a = *(const bf16x8*)(&Klds[cur][kr * 64 + (d0c ^ ((kr & 7) << 3))]);
        s0 = MFMA16(a, qfrag[0][c], s0);
        s1 = MFMA16(a, qfrag[1][c], s1);
      }
      #pragma unroll
      for (int r = 0; r < 4; ++r) {
        rsum0 += __builtin_amdgcn_exp2f(s0[r]);
        rsum1 += __builtin_amdgcn_exp2f(s1[r]);
      }
    }
    if (kt + 1 < NT) { cvtK(); writeKlds(cur ^ 1); maybeWriteKb(kt + 1); }
    sync_lds();
  }
  rsum0 += __shfl_xor(rsum0, 16); rsum0 += __shfl_xor(rsum0, 32);
  rsum1 += __shfl_xor(rsum1, 16); rsum1 += __shfl_xor(rsum1, 32);
  if (lane < 16) {
    float* ro = rinv_out + (long)head * L + qrow0;
    ro[qr]      = 1.f / rsum0;
    ro[16 + qr] = 1.f / rsum1;
  }
}

// ====== main: 512 threads, 256q x 256k macro-tiles, 1KB attn row-runs ======
__global__ __launch_bounds__(512, 2)
void sdpa_main(const short* __restrict__ Qb, const short* __restrict__ Kb,
               const short* __restrict__ Vtb, const float* __restrict__ rinv_ws,
               float* __restrict__ out, float* __restrict__ attn)
{
  __shared__ short Klds[KT3 * D];       // [kr 256][d 64]   32 KB
  __shared__ short Vlds[D * KT3];       // [d 64][k 256]    32 KB
  __shared__ short Plds[8][16 * KT3];   // per-wave [q16][k256]  64 KB

  const int t = threadIdx.x, lane = t & 63, w = t >> 6;   // 8 waves
  const int qr = lane & 15, g = lane >> 4;

  const int krow = t >> 1, kd0 = (t & 1) * 32;   // K staging: 2 threads/row
  const int vd   = t >> 3, vk0 = (t & 7) * 32;   // V staging: 8 threads/row

  for (int item = blockIdx.x; item < NHEAD * NQT3; item += GRID_MAIN) {
    const int wid = ((item & 7) << 6) | (item >> 3);   // XCD-affine, bijective
    const int head = wid >> 3, qt = wid & 7;
    const long hoff = (long)head * L * D;
    const int qrow0 = qt * QB3 + w * 32;               // wave owns 32 q-rows

    const float rinv0 = rinv_ws[(long)head * L + qrow0 + qr];
    const float rinv1 = rinv_ws[(long)head * L + qrow0 + 16 + qr];

    bf16x8 qfrag[2][2];
    #pragma unroll
    for (int h = 0; h < 2; ++h) {
      const short* qbp = Qb + hoff + (long)(qrow0 + 16 * h + qr) * D + g * 8;
      qfrag[h][0] = *(const bf16x8*)qbp;
      qfrag[h][1] = *(const bf16x8*)(qbp + 32);
    }

    const short* Kbase = Kb + hoff;
    const short* Vbase = Vtb + (long)head * D * L;

    bf16x8 kreg[4], vreg[4];

    auto loadK = [&](int kt) {
      const short* kp = Kbase + (long)(kt * KT3 + krow) * D + kd0;
      #pragma unroll
      for (int i = 0; i < 4; ++i) kreg[i] = *(const bf16x8*)(kp + 8 * i);
    };
    auto writeK = [&]() {
      const int sw = (krow & 7) << 3;
      #pragma unroll
      for (int i = 0; i < 4; ++i)
        *(bf16x8*)(&Klds[krow * 64 + ((kd0 + 8 * i) ^ sw)]) = kreg[i];
    };
    auto loadV = [&](int kt) {
      const short* vp = Vbase + (long)vd * L + kt * KT3 + vk0;
      #pragma unroll
      for (int i = 0; i < 4; ++i) vreg[i] = *(const bf16x8*)(vp + 8 * i);
    };
    auto writeV = [&]() {
      const int sw = (vd & 7) << 3;
      #pragma unroll
      for (int i = 0; i < 4; ++i)
        *(bf16x8*)(&Vlds[vd * 256 + ((vk0 + 8 * i) ^ sw)]) = vreg[i];
    };

    f32x4 o0[4] = {{0.f,0.f,0.f,0.f},{0.f,0.f,0.f,0.f},{0.f,0.f,0.f,0.f},{0.f,0.f,0.f,0.f}};
    f32x4 o1[4] = {{0.f,0.f,0.f,0.f},{0.f,0.f,0.f,0.f},{0.f,0.f,0.f,0.f},{0.f,0.f,0.f,0.f}};
    float* apb = attn + (long)head * L * L + (long)qrow0 * L;

    loadK(0); loadV(0);
    sync_lds();               // guard previous item's LDS reads
    writeK(); writeV();
    sync_lds();

    for (int kt = 0; kt < NT3; ++kt) {
      if (kt + 1 < NT3) { loadK(kt + 1); loadV(kt + 1); }   // reg prefetch

      #pragma unroll
      for (int h = 0; h < 2; ++h) {
        // ---- S: 16 fragments x 16 k = 256 k for this q-half ----
        f32x4 s[16];
        #pragma unroll
        for (int f = 0; f < 16; ++f) {
          s[f] = (f32x4){0.f, 0.f, 0.f, 0.f};
          int kr = f * 16 + qr;
          #pragma unroll
          for (int c = 0; c < 2; ++c) {
            int d0c = g * 8 + 32 * c;
            bf16x8 a = *(const bf16x8*)(&Klds[kr * 64 + (d0c ^ ((kr & 7) << 3))]);
            s[f] = MFMA16(a, qfrag[h][c], s[f]);
          }
        }
        const float rinv = h ? rinv1 : rinv0;
        // ---- P -> Plds (bf16) ----
        #pragma unroll
        for (int f = 0; f < 16; ++f) {
          bf16x4 p;
          #pragma unroll
          for (int r = 0; r < 4; ++r)
            p[r] = f2bf(__builtin_amdgcn_exp2f(s[f][r]) * rinv);
          int k0 = f * 16 + g * 4;
          *(bf16x4*)(&Plds[w][qr * 256 + (k0 ^ ((qr & 7) << 3))]) = p;
        }
        __builtin_amdgcn_wave_barrier();   // P writes before reads (wave-private)

        // ---- attn: each store instruction = one full 1KB row-run ----
        {
          float* ap = apb + (long)(16 * h) * L + (long)kt * KT3;
          const int col4 = lane * 4;
          #pragma unroll
          for (int r = 0; r < 16; ++r) {
            bf16x4 pb = *(const bf16x4*)(&Plds[w][r * 256 + (col4 ^ ((r & 7) << 3))]);
            f32x4 pf;
            #pragma unroll
            for (int j = 0; j < 4; ++j) pf[j] = bf2f(pb[j]);
            *(f32x4*)(ap + (long)r * L + col4) = pf;
          }
        }

        // ---- PV: O(16q x 64d) += P(16x256) * V(256x64) ----
        #pragma unroll
        for (int kc = 0; kc < 8; ++kc) {
          int k0 = kc * 32 + g * 8;
          bf16x8 pa = *(const bf16x8*)(&Plds[w][qr * 256 + (k0 ^ ((qr & 7) << 3))]);
          #pragma unroll
          for (int fr = 0; fr < 4; ++fr) {
            int d = fr * 16 + qr;
            bf16x8 vb = *(const bf16x8*)(&Vlds[d * 256 + (k0 ^ ((d & 7) << 3))]);
            if (h == 0) o0[fr] = MFMA16(pa, vb, o0[fr]);
            else        o1[fr] = MFMA16(pa, vb, o1[fr]);
          }
        }
        __builtin_amdgcn_wave_barrier();   // PV reads before next half's P writes
      }

      sync_lds();                          // all waves done with Klds/Vlds
      if (kt + 1 < NT3) { writeK(); writeV(); sync_lds(); }
    }

    float* op = out + hoff + (long)qrow0 * D;
    #pragma unroll
    for (int fr = 0; fr < 4; ++fr)
      #pragma unroll
      for (int r = 0; r < 4; ++r) {
        op[(long)(g * 4 + r) * D + fr * 16 + qr]      = o0[fr][r];
        op[(long)(16 + g * 4 + r) * D + fr * 16 + qr] = o1[fr][r];
      }
  }
}

// ============ fallback (round-5 proven kernel, f32-staged) ============
__global__ __launch_bounds__(256, 4)
void sdpa_fused(const float* __restrict__ Q, const float* __restrict__ K,
                const float* __restrict__ V, float* __restrict__ out,
                float* __restrict__ attn)
{
  __shared__ short Klds[2][KT * D];
  __shared__ short Vlds[2][D * KT];
  __shared__ short Plds[4][16 * KT];

  const int t = threadIdx.x, lane = t & 63, w = t >> 6;
  const int qr = lane & 15, g = lane >> 4;
  const int head = blockIdx.x >> 5, qt = blockIdx.x & 31;
  const long hoff = (long)head * L * D;
  const int qrow0 = qt * 64 + w * 16;

  bf16x8 qfrag[2];
  {
    const float* qp = Q + hoff + (long)(qrow0 + qr) * D + g * 8;
    #pragma unroll
    for (int c = 0; c < 2; ++c)
      #pragma unroll
      for (int j = 0; j < 8; ++j)
        qfrag[c][j] = f2bf(qp[32 * c + j] * QSCALE);
  }

  const float* Kbase = K + hoff;
  const float* Vbase = V + hoff;
  f32x4 kreg[4], vreg[4];

  auto loadK = [&](int kt) {
    const float* kp = Kbase + (long)kt * KT * D;
    #pragma unroll
    for (int c = 0; c < 4; ++c)
      kreg[c] = *(const f32x4*)(kp + (t + 256 * c) * 4);
  };
  auto writeK = [&](int buf) {
    #pragma unroll
    for (int c = 0; c < 4; ++c) {
      int f = t + 256 * c;
      int kr = f >> 4, col = (f & 15) * 4;
      bf16x4 y;
      #pragma unroll
      for (int i = 0; i < 4; ++i) y[i] = f2bf(kreg[c][i]);
      *(bf16x4*)(&Klds[buf][kr * 64 + (col ^ ((kr & 7) << 3))]) = y;
    }
  };
  auto loadV = [&](int kt) {
    const float* vp = Vbase + (long)kt * KT * D;
    int kr0 = (t >> 4) * 4, d0 = (t & 15) * 4;
    #pragma unroll
    for (int i = 0; i < 4; ++i)
      vreg[i] = *(const f32x4*)(vp + (kr0 + i) * D + d0);
  };
  auto writeV = [&](int buf) {
    int kr0 = (t >> 4) * 4, d0 = (t & 15) * 4;
    #pragma unroll
    for (int j = 0; j < 4; ++j) {
      bf16x4 y;
      #pragma unroll
      for (int i = 0; i < 4; ++i) y[i] = f2bf(vreg[i][j]);
      int d = d0 + j;
      *(bf16x4*)(&Vlds[buf][d * 64 + (kr0 ^ ((d & 7) << 3))]) = y;
    }
  };
  auto computeS = [&](int buf, f32x4 s[4]) {
    #pragma unroll
    for (int f = 0; f < 4; ++f) {
      s[f] = (f32x4){0.f, 0.f, 0.f, 0.f};
      int kr = f * 16 + qr;
      #pragma unroll
      for (int c = 0; c < 2; ++c) {
        int d0c = g * 8 + 32 * c;
        bf16x8 a = *(const bf16x8*)(&Klds[buf][kr * 64 + (d0c ^ ((kr & 7) << 3))]);
        s[f] = MFMA16(a, qfrag[c], s[f]);
      }
    }
  };

  loadK(0); writeK(0);
  sync_lds();
  float rsum = 0.f;
  for (int kt = 0; kt < NT; ++kt) {
    const int cur = kt & 1;
    if (kt + 1 < NT) loadK(kt + 1);
    f32x4 s[4];
    computeS(cur, s);
    #pragma unroll
    for (int f = 0; f < 4; ++f)
      #pragma unroll
      for (int r = 0; r < 4; ++r)
        rsum += __builtin_amdgcn_exp2f(s[f][r]);
    if (kt + 1 < NT) writeK(cur ^ 1);
    sync_lds();
  }
  rsum += __shfl_xor(rsum, 16);
  rsum += __shfl_xor(rsum, 32);
  const float rinv = 1.f / rsum;

  f32x4 o[4] = {{0.f,0.f,0.f,0.f},{0.f,0.f,0.f,0.f},{0.f,0.f,0.f,0.f},{0.f,0.f,0.f,0.f}};
  float* ap_base = attn + (long)head * L * L + (long)qrow0 * L;

  loadK(0); loadV(0);
  writeK(0); writeV(0);
  sync_lds();

  for (int kt = 0; kt < NT; ++kt) {
    const int cur = kt & 1;
    if (kt + 1 < NT) { loadK(kt + 1); loadV(kt + 1); }

    f32x4 s[4];
    computeS(cur, s);

    #pragma unroll
    for (int f = 0; f < 4; ++f) {
      bf16x4 p;
      #pragma unroll
      for (int r = 0; r < 4; ++r)
        p[r] = f2bf(__builtin_amdgcn_exp2f(s[f][r]) * rinv);
      int k0 = f * 16 + g * 4;
      *(bf16x4*)(&Plds[w][qr * 64 + (k0 ^ ((qr & 7) << 3))]) = p;
    }
    __builtin_amdgcn_wave_barrier();

    float* ap = ap_base + (long)kt * KT;
    #pragma unroll
    for (int i = 0; i < 4; ++i) {
      int r = 4 * i + g, col = 4 * qr;
      bf16x4 pb = *(const bf16x4*)(&Plds[w][r * 64 + (col ^ ((r & 7) << 3))]);
      f32x4 pf;
      #pragma unroll
      for (int j = 0; j < 4; ++j) pf[j] = bf2f(pb[j]);
      *(f32x4*)(ap + (long)r * L + col) = pf;
    }

    #pragma unroll
    for (int kc = 0; kc < 2; ++kc) {
      int k0 = kc * 32 + g * 8;
      bf16x8 pa = *(const bf16x8*)(&Plds[w][qr * 64 + (k0 ^ ((qr & 7) << 3))]);
      #pragma unroll
      for (int fr = 0; fr < 4; ++fr) {
        int d = fr * 16 + qr;
        bf16x8 vb = *(const bf16x8*)(&Vlds[cur][d * 64 + (k0 ^ ((d & 7) << 3))]);
        o[fr] = MFMA16(pa, vb, o[fr]);
      }
    }

    if (kt + 1 < NT) { writeK(cur ^ 1); writeV(cur ^ 1); }
    sync_lds();
  }

  float* op = out + hoff + (long)qrow0 * D;
  #pragma unroll
  for (int fr = 0; fr < 4; ++fr)
    #pragma unroll
    for (int r = 0; r < 4; ++r) {
      int qq = g * 4 + r;
      op[(long)qq * D + fr * 16 + qr] = o[fr][r];
    }
}

extern "C" void kernel_launch(void* const* d_in, const int* in_sizes, int n_in,
                              void* d_out, int out_size, void* d_ws, size_t ws_size,
                              hipStream_t stream) {
  const float* q = (const float*)d_in[0];
  const float* k = (const float*)d_in[1];
  const float* v = (const float*)d_in[2];
  float* out  = (float*)d_out;                          // (B,H,L,D)
  float* attn = (float*)d_out + (size_t)NHEAD * L * D;  // (B,H,L,L)

  if (ws_size >= WS_NEED) {
    short* Qb   = (short*)d_ws;
    short* Kb   = Qb + BF_ELEMS;
    short* Vtb  = Kb + BF_ELEMS;
    float* rinv = (float*)(Vtb + BF_ELEMS);
    hipLaunchKernelGGL(sdpa_prepV,   dim3(NHEAD * NT),  dim3(256), 0, stream, v, Vtb);
    hipLaunchKernelGGL(sdpa_rowsum2, dim3(NHEAD * NQT), dim3(256), 0, stream, q, k, Qb, Kb, rinv);
    hipLaunchKernelGGL(sdpa_main,    dim3(GRID_MAIN),   dim3(512), 0, stream, Qb, Kb, Vtb, rinv, out, attn);
  } else {
    hipLaunchKernelGGL(sdpa_fused, dim3(NHEAD * NT), dim3(256), 0, stream, q, k, v, out, attn);
  }
}

// Round 14
// 302.469 us; speedup vs baseline: 1.4018x; 1.0091x over previous
//
#include <hip/hip_runtime.h>
#include <hip/hip_bf16.h>

typedef __attribute__((ext_vector_type(4))) float  f32x4;
typedef __attribute__((ext_vector_type(8))) short  bf16x8;
typedef __attribute__((ext_vector_type(4))) short  bf16x4;

#define MFMA16(a, b, c) __builtin_amdgcn_mfma_f32_16x16x32_bf16((a), (b), (c), 0, 0, 0)

__device__ __forceinline__ short f2bf(float f) {
  return __builtin_bit_cast(short, __float2bfloat16(f));
}
__device__ __forceinline__ float bf2f(short b) {
  return __builtin_bit_cast(float, ((unsigned)(unsigned short)b) << 16);
}

__device__ __forceinline__ void sync_lds() {
  asm volatile("s_waitcnt lgkmcnt(0)" ::: "memory");
  __builtin_amdgcn_s_barrier();
  asm volatile("" ::: "memory");
}

constexpr int L = 2048, D = 64, KT = 64, NT = L / KT;    // rowsum tiling
constexpr int KT3 = 256, NT3 = L / KT3;                  // main macro-tiles (1KB runs)
constexpr int NHEAD = 64;
constexpr int QB = 128, NQT = L / QB;                    // rowsum q-tiles (grid 1024)
constexpr int QB3 = 256, NQT3 = L / QB3;                 // main q-tiles: 512 items
constexpr int GRID_MAIN = 256;                           // 1 block/CU, 2 items each
constexpr float QSCALE = 0.18033688011112042f;           // 0.125*log2(e)
constexpr size_t BF_ELEMS = (size_t)NHEAD * L * D;
constexpr size_t WS_NEED = 3 * BF_ELEMS * sizeof(short) + (size_t)NHEAD * L * sizeof(float);

// == rowsum2: f32 Q/K/V in; rinv out; Qb/Kb/Vtb bf16 written as side effects ==
__global__ __launch_bounds__(256, 4)
void sdpa_rowsum2(const float* __restrict__ Qf, const float* __restrict__ Kf,
                  const float* __restrict__ Vf,
                  short* __restrict__ Qb, short* __restrict__ Kb,
                  short* __restrict__ Vtb, float* __restrict__ rinv_out)
{
  __shared__ short Klds[2][KT * D];

  const int t = threadIdx.x, lane = t & 63, w = t >> 6;
  const int qr = lane & 15, g = lane >> 4;

  const int bid = blockIdx.x;
  const int wid = ((bid & 7) << 7) | (bid >> 3);
  const int head = wid >> 4, qt = wid & 15;
  const long hoff = (long)head * L * D;
  const int qrow0 = qt * QB + w * 32;

  // --- stream-convert this block's 128 Q rows -> Qb ---
  {
    const float* qp = Qf + hoff + (long)qt * QB * D + t * 32;
    short*       qo = Qb + hoff + (long)qt * QB * D + t * 32;
    #pragma unroll
    for (int c = 0; c < 4; ++c) {
      f32x4 a = *(const f32x4*)(qp + c * 8);
      f32x4 b = *(const f32x4*)(qp + c * 8 + 4);
      bf16x8 y;
      #pragma unroll
      for (int j = 0; j < 4; ++j) {
        y[j]     = f2bf(a[j] * QSCALE);
        y[4 + j] = f2bf(b[j] * QSCALE);
      }
      *(bf16x8*)(qo + c * 8) = y;
    }
  }

  // --- folded prepV: transpose this block's 128 k-rows of V -> Vtb ---
  // (in-register 4x4 transpose; drains under the K-loop compute below)
  {
    short* VtH = Vtb + (long)head * D * L;
    #pragma unroll
    for (int s = 0; s < 2; ++s) {
      const int kbase = qt * QB + s * 64;
      const int kr0 = (t >> 4) * 4, d0 = (t & 15) * 4;
      const float* vp = Vf + hoff + (long)(kbase + kr0) * D + d0;
      f32x4 r[4];
      #pragma unroll
      for (int i = 0; i < 4; ++i) r[i] = *(const f32x4*)(vp + i * D);
      #pragma unroll
      for (int j = 0; j < 4; ++j) {
        bf16x4 y;
        #pragma unroll
        for (int i = 0; i < 4; ++i) y[i] = f2bf(r[i][j]);
        *(bf16x4*)(VtH + (long)(d0 + j) * L + kbase + kr0) = y;
      }
    }
  }

  bf16x8 qfrag[2][2];
  #pragma unroll
  for (int h = 0; h < 2; ++h)
    #pragma unroll
    for (int c = 0; c < 2; ++c) {
      const float* qp = Qf + hoff + (long)(qrow0 + 16 * h + qr) * D + g * 8 + 32 * c;
      f32x4 a = *(const f32x4*)qp;
      f32x4 b = *(const f32x4*)(qp + 4);
      #pragma unroll
      for (int j = 0; j < 4; ++j) {
        qfrag[h][c][j]     = f2bf(a[j] * QSCALE);
        qfrag[h][c][4 + j] = f2bf(b[j] * QSCALE);
      }
    }

  const float* KfH = Kf + hoff;
  short*       KbH = Kb + hoff;
  const int krow = t >> 2, kd0 = (t & 3) * 16;
  f32x4 kf[4];
  bf16x8 kb0, kb1;

  auto loadK = [&](int kt) {
    const float* kp = KfH + (long)(kt * KT + krow) * D + kd0;
    #pragma unroll
    for (int i = 0; i < 4; ++i) kf[i] = *(const f32x4*)(kp + 4 * i);
  };
  auto cvtK = [&]() {
    #pragma unroll
    for (int j = 0; j < 8; ++j) {
      kb0[j] = f2bf(kf[j >> 2][j & 3]);
      kb1[j] = f2bf(kf[2 + (j >> 2)][j & 3]);
    }
  };
  auto writeKlds = [&](int buf) {
    const int sw = (krow & 7) << 3;
    *(bf16x8*)(&Klds[buf][krow * 64 + (kd0 ^ sw)])       = kb0;
    *(bf16x8*)(&Klds[buf][krow * 64 + ((kd0 + 8) ^ sw)]) = kb1;
  };
  auto maybeWriteKb = [&](int kt) {   // each block owns k-tiles 2qt, 2qt+1
    if ((kt >> 1) == qt) {
      short* ko = KbH + (long)(kt * KT + krow) * D + kd0;
      *(bf16x8*)ko = kb0;
      *(bf16x8*)(ko + 8) = kb1;
    }
  };

  loadK(0); cvtK(); writeKlds(0); maybeWriteKb(0);
  sync_lds();
  float rsum0 = 0.f, rsum1 = 0.f;
  for (int kt = 0; kt < NT; ++kt) {
    const int cur = kt & 1;
    if (kt + 1 < NT) loadK(kt + 1);
    #pragma unroll
    for (int f = 0; f < 4; ++f) {
      f32x4 s0 = (f32x4){0.f,0.f,0.f,0.f};
      f32x4 s1 = (f32x4){0.f,0.f,0.f,0.f};
      int kr = f * 16 + qr;
      #pragma unroll
      for (int c = 0; c < 2; ++c) {
        int d0c = g * 8 + 32 * c;
        bf16x8 a = *(const bf16x8*)(&Klds[cur][kr * 64 + (d0c ^ ((kr & 7) << 3))]);
        s0 = MFMA16(a, qfrag[0][c], s0);
        s1 = MFMA16(a, qfrag[1][c], s1);
      }
      #pragma unroll
      for (int r = 0; r < 4; ++r) {
        rsum0 += __builtin_amdgcn_exp2f(s0[r]);
        rsum1 += __builtin_amdgcn_exp2f(s1[r]);
      }
    }
    if (kt + 1 < NT) { cvtK(); writeKlds(cur ^ 1); maybeWriteKb(kt + 1); }
    sync_lds();
  }
  rsum0 += __shfl_xor(rsum0, 16); rsum0 += __shfl_xor(rsum0, 32);
  rsum1 += __shfl_xor(rsum1, 16); rsum1 += __shfl_xor(rsum1, 32);
  if (lane < 16) {
    float* ro = rinv_out + (long)head * L + qrow0;
    ro[qr]      = 1.f / rsum0;
    ro[16 + qr] = 1.f / rsum1;
  }
}

// ====== main: 512 threads, 256q x 256k macro-tiles, 1KB attn row-runs ======
__global__ __launch_bounds__(512, 2)
void sdpa_main(const short* __restrict__ Qb, const short* __restrict__ Kb,
               const short* __restrict__ Vtb, const float* __restrict__ rinv_ws,
               float* __restrict__ out, float* __restrict__ attn)
{
  __shared__ short Klds[KT3 * D];       // [kr 256][d 64]   32 KB
  __shared__ short Vlds[D * KT3];       // [d 64][k 256]    32 KB
  __shared__ short Plds[8][16 * KT3];   // per-wave [q16][k256]  64 KB

  const int t = threadIdx.x, lane = t & 63, w = t >> 6;   // 8 waves
  const int qr = lane & 15, g = lane >> 4;

  const int krow = t >> 1, kd0 = (t & 1) * 32;   // K staging: 2 threads/row
  const int vd   = t >> 3, vk0 = (t & 7) * 32;   // V staging: 8 threads/row

  for (int item = blockIdx.x; item < NHEAD * NQT3; item += GRID_MAIN) {
    const int wid = ((item & 7) << 6) | (item >> 3);   // XCD-affine, bijective
    const int head = wid >> 3, qt = wid & 7;
    const long hoff = (long)head * L * D;
    const int qrow0 = qt * QB3 + w * 32;               // wave owns 32 q-rows

    const float rinv0 = rinv_ws[(long)head * L + qrow0 + qr];
    const float rinv1 = rinv_ws[(long)head * L + qrow0 + 16 + qr];

    bf16x8 qfrag[2][2];
    #pragma unroll
    for (int h = 0; h < 2; ++h) {
      const short* qbp = Qb + hoff + (long)(qrow0 + 16 * h + qr) * D + g * 8;
      qfrag[h][0] = *(const bf16x8*)qbp;
      qfrag[h][1] = *(const bf16x8*)(qbp + 32);
    }

    const short* Kbase = Kb + hoff;
    const short* Vbase = Vtb + (long)head * D * L;

    bf16x8 kreg[4], vreg[4];

    auto loadK = [&](int kt) {
      const short* kp = Kbase + (long)(kt * KT3 + krow) * D + kd0;
      #pragma unroll
      for (int i = 0; i < 4; ++i) kreg[i] = *(const bf16x8*)(kp + 8 * i);
    };
    auto writeK = [&]() {
      const int sw = (krow & 7) << 3;
      #pragma unroll
      for (int i = 0; i < 4; ++i)
        *(bf16x8*)(&Klds[krow * 64 + ((kd0 + 8 * i) ^ sw)]) = kreg[i];
    };
    auto loadV = [&](int kt) {
      const short* vp = Vbase + (long)vd * L + kt * KT3 + vk0;
      #pragma unroll
      for (int i = 0; i < 4; ++i) vreg[i] = *(const bf16x8*)(vp + 8 * i);
    };
    auto writeV = [&]() {
      const int sw = (vd & 7) << 3;
      #pragma unroll
      for (int i = 0; i < 4; ++i)
        *(bf16x8*)(&Vlds[vd * 256 + ((vk0 + 8 * i) ^ sw)]) = vreg[i];
    };

    f32x4 o0[4] = {{0.f,0.f,0.f,0.f},{0.f,0.f,0.f,0.f},{0.f,0.f,0.f,0.f},{0.f,0.f,0.f,0.f}};
    f32x4 o1[4] = {{0.f,0.f,0.f,0.f},{0.f,0.f,0.f,0.f},{0.f,0.f,0.f,0.f},{0.f,0.f,0.f,0.f}};
    float* apb = attn + (long)head * L * L + (long)qrow0 * L;

    loadK(0); loadV(0);
    sync_lds();               // guard previous item's LDS reads
    writeK(); writeV();
    sync_lds();

    for (int kt = 0; kt < NT3; ++kt) {
      if (kt + 1 < NT3) { loadK(kt + 1); loadV(kt + 1); }   // reg prefetch

      #pragma unroll
      for (int h = 0; h < 2; ++h) {
        // ---- S: 16 fragments x 16 k = 256 k for this q-half ----
        f32x4 s[16];
        #pragma unroll
        for (int f = 0; f < 16; ++f) {
          s[f] = (f32x4){0.f, 0.f, 0.f, 0.f};
          int kr = f * 16 + qr;
          #pragma unroll
          for (int c = 0; c < 2; ++c) {
            int d0c = g * 8 + 32 * c;
            bf16x8 a = *(const bf16x8*)(&Klds[kr * 64 + (d0c ^ ((kr & 7) << 3))]);
            s[f] = MFMA16(a, qfrag[h][c], s[f]);
          }
        }
        const float rinv = h ? rinv1 : rinv0;
        // ---- P -> Plds (bf16) ----
        #pragma unroll
        for (int f = 0; f < 16; ++f) {
          bf16x4 p;
          #pragma unroll
          for (int r = 0; r < 4; ++r)
            p[r] = f2bf(__builtin_amdgcn_exp2f(s[f][r]) * rinv);
          int k0 = f * 16 + g * 4;
          *(bf16x4*)(&Plds[w][qr * 256 + (k0 ^ ((qr & 7) << 3))]) = p;
        }
        __builtin_amdgcn_wave_barrier();   // P writes before reads (wave-private)

        // ---- attn: each store instruction = one full 1KB row-run ----
        {
          float* ap = apb + (long)(16 * h) * L + (long)kt * KT3;
          const int col4 = lane * 4;
          #pragma unroll
          for (int r = 0; r < 16; ++r) {
            bf16x4 pb = *(const bf16x4*)(&Plds[w][r * 256 + (col4 ^ ((r & 7) << 3))]);
            f32x4 pf;
            #pragma unroll
            for (int j = 0; j < 4; ++j) pf[j] = bf2f(pb[j]);
            *(f32x4*)(ap + (long)r * L + col4) = pf;
          }
        }

        // ---- PV: O(16q x 64d) += P(16x256) * V(256x64) ----
        #pragma unroll
        for (int kc = 0; kc < 8; ++kc) {
          int k0 = kc * 32 + g * 8;
          bf16x8 pa = *(const bf16x8*)(&Plds[w][qr * 256 + (k0 ^ ((qr & 7) << 3))]);
          #pragma unroll
          for (int fr = 0; fr < 4; ++fr) {
            int d = fr * 16 + qr;
            bf16x8 vb = *(const bf16x8*)(&Vlds[d * 256 + (k0 ^ ((d & 7) << 3))]);
            if (h == 0) o0[fr] = MFMA16(pa, vb, o0[fr]);
            else        o1[fr] = MFMA16(pa, vb, o1[fr]);
          }
        }
        __builtin_amdgcn_wave_barrier();   // PV reads before next half's P writes
      }

      sync_lds();                          // all waves done with Klds/Vlds
      if (kt + 1 < NT3) { writeK(); writeV(); sync_lds(); }
    }

    float* op = out + hoff + (long)qrow0 * D;
    #pragma unroll
    for (int fr = 0; fr < 4; ++fr)
      #pragma unroll
      for (int r = 0; r < 4; ++r) {
        op[(long)(g * 4 + r) * D + fr * 16 + qr]      = o0[fr][r];
        op[(long)(16 + g * 4 + r) * D + fr * 16 + qr] = o1[fr][r];
      }
  }
}

// ============ fallback (round-5 proven kernel, f32-staged) ============
__global__ __launch_bounds__(256, 4)
void sdpa_fused(const float* __restrict__ Q, const float* __restrict__ K,
                const float* __restrict__ V, float* __restrict__ out,
                float* __restrict__ attn)
{
  __shared__ short Klds[2][KT * D];
  __shared__ short Vlds[2][D * KT];
  __shared__ short Plds[4][16 * KT];

  const int t = threadIdx.x, lane = t & 63, w = t >> 6;
  const int qr = lane & 15, g = lane >> 4;
  const int head = blockIdx.x >> 5, qt = blockIdx.x & 31;
  const long hoff = (long)head * L * D;
  const int qrow0 = qt * 64 + w * 16;

  bf16x8 qfrag[2];
  {
    const float* qp = Q + hoff + (long)(qrow0 + qr) * D + g * 8;
    #pragma unroll
    for (int c = 0; c < 2; ++c)
      #pragma unroll
      for (int j = 0; j < 8; ++j)
        qfrag[c][j] = f2bf(qp[32 * c + j] * QSCALE);
  }

  const float* Kbase = K + hoff;
  const float* Vbase = V + hoff;
  f32x4 kreg[4], vreg[4];

  auto loadK = [&](int kt) {
    const float* kp = Kbase + (long)kt * KT * D;
    #pragma unroll
    for (int c = 0; c < 4; ++c)
      kreg[c] = *(const f32x4*)(kp + (t + 256 * c) * 4);
  };
  auto writeK = [&](int buf) {
    #pragma unroll
    for (int c = 0; c < 4; ++c) {
      int f = t + 256 * c;
      int kr = f >> 4, col = (f & 15) * 4;
      bf16x4 y;
      #pragma unroll
      for (int i = 0; i < 4; ++i) y[i] = f2bf(kreg[c][i]);
      *(bf16x4*)(&Klds[buf][kr * 64 + (col ^ ((kr & 7) << 3))]) = y;
    }
  };
  auto loadV = [&](int kt) {
    const float* vp = Vbase + (long)kt * KT * D;
    int kr0 = (t >> 4) * 4, d0 = (t & 15) * 4;
    #pragma unroll
    for (int i = 0; i < 4; ++i)
      vreg[i] = *(const f32x4*)(vp + (kr0 + i) * D + d0);
  };
  auto writeV = [&](int buf) {
    int kr0 = (t >> 4) * 4, d0 = (t & 15) * 4;
    #pragma unroll
    for (int j = 0; j < 4; ++j) {
      bf16x4 y;
      #pragma unroll
      for (int i = 0; i < 4; ++i) y[i] = f2bf(vreg[i][j]);
      int d = d0 + j;
      *(bf16x4*)(&Vlds[buf][d * 64 + (kr0 ^ ((d & 7) << 3))]) = y;
    }
  };
  auto computeS = [&](int buf, f32x4 s[4]) {
    #pragma unroll
    for (int f = 0; f < 4; ++f) {
      s[f] = (f32x4){0.f, 0.f, 0.f, 0.f};
      int kr = f * 16 + qr;
      #pragma unroll
      for (int c = 0; c < 2; ++c) {
        int d0c = g * 8 + 32 * c;
        bf16x8 a = *(const bf16x8*)(&Klds[buf][kr * 64 + (d0c ^ ((kr & 7) << 3))]);
        s[f] = MFMA16(a, qfrag[c], s[f]);
      }
    }
  };

  loadK(0); writeK(0);
  sync_lds();
  float rsum = 0.f;
  for (int kt = 0; kt < NT; ++kt) {
    const int cur = kt & 1;
    if (kt + 1 < NT) loadK(kt + 1);
    f32x4 s[4];
    computeS(cur, s);
    #pragma unroll
    for (int f = 0; f < 4; ++f)
      #pragma unroll
      for (int r = 0; r < 4; ++r)
        rsum += __builtin_amdgcn_exp2f(s[f][r]);
    if (kt + 1 < NT) writeK(cur ^ 1);
    sync_lds();
  }
  rsum += __shfl_xor(rsum, 16);
  rsum += __shfl_xor(rsum, 32);
  const float rinv = 1.f / rsum;

  f32x4 o[4] = {{0.f,0.f,0.f,0.f},{0.f,0.f,0.f,0.f},{0.f,0.f,0.f,0.f},{0.f,0.f,0.f,0.f}};
  float* ap_base = attn + (long)head * L * L + (long)qrow0 * L;

  loadK(0); loadV(0);
  writeK(0); writeV(0);
  sync_lds();

  for (int kt = 0; kt < NT; ++kt) {
    const int cur = kt & 1;
    if (kt + 1 < NT) { loadK(kt + 1); loadV(kt + 1); }

    f32x4 s[4];
    computeS(cur, s);

    #pragma unroll
    for (int f = 0; f < 4; ++f) {
      bf16x4 p;
      #pragma unroll
      for (int r = 0; r < 4; ++r)
        p[r] = f2bf(__builtin_amdgcn_exp2f(s[f][r]) * rinv);
      int k0 = f * 16 + g * 4;
      *(bf16x4*)(&Plds[w][qr * 64 + (k0 ^ ((qr & 7) << 3))]) = p;
    }
    __builtin_amdgcn_wave_barrier();

    float* ap = ap_base + (long)kt * KT;
    #pragma unroll
    for (int i = 0; i < 4; ++i) {
      int r = 4 * i + g, col = 4 * qr;
      bf16x4 pb = *(const bf16x4*)(&Plds[w][r * 64 + (col ^ ((r & 7) << 3))]);
      f32x4 pf;
      #pragma unroll
      for (int j = 0; j < 4; ++j) pf[j] = bf2f(pb[j]);
      *(f32x4*)(ap + (long)r * L + col) = pf;
    }

    #pragma unroll
    for (int kc = 0; kc < 2; ++kc) {
      int k0 = kc * 32 + g * 8;
      bf16x8 pa = *(const bf16x8*)(&Plds[w][qr * 64 + (k0 ^ ((qr & 7) << 3))]);
      #pragma unroll
      for (int fr = 0; fr < 4; ++fr) {
        int d = fr * 16 + qr;
        bf16x8 vb = *(const bf16x8*)(&Vlds[cur][d * 64 + (k0 ^ ((d & 7) << 3))]);
        o[fr] = MFMA16(pa, vb, o[fr]);
      }
    }

    if (kt + 1 < NT) { writeK(cur ^ 1); writeV(cur ^ 1); }
    sync_lds();
  }

  float* op = out + hoff + (long)qrow0 * D;
  #pragma unroll
  for (int fr = 0; fr < 4; ++fr)
    #pragma unroll
    for (int r = 0; r < 4; ++r) {
      int qq = g * 4 + r;
      op[(long)qq * D + fr * 16 + qr] = o[fr][r];
    }
}

extern "C" void kernel_launch(void* const* d_in, const int* in_sizes, int n_in,
                              void* d_out, int out_size, void* d_ws, size_t ws_size,
                              hipStream_t stream) {
  const float* q = (const float*)d_in[0];
  const float* k = (const float*)d_in[1];
  const float* v = (const float*)d_in[2];
  float* out  = (float*)d_out;                          // (B,H,L,D)
  float* attn = (float*)d_out + (size_t)NHEAD * L * D;  // (B,H,L,L)

  if (ws_size >= WS_NEED) {
    short* Qb   = (short*)d_ws;
    short* Kb   = Qb + BF_ELEMS;
    short* Vtb  = Kb + BF_ELEMS;
    float* rinv = (float*)(Vtb + BF_ELEMS);
    hipLaunchKernelGGL(sdpa_rowsum2, dim3(NHEAD * NQT), dim3(256), 0, stream,
                       q, k, v, Qb, Kb, Vtb, rinv);
    hipLaunchKernelGGL(sdpa_main,    dim3(GRID_MAIN),   dim3(512), 0, stream,
                       Qb, Kb, Vtb, rinv, out, attn);
  } else {
    hipLaunchKernelGGL(sdpa_fused, dim3(NHEAD * NT), dim3(256), 0, stream, q, k, v, out, attn);
  }
}